// Round 1
// baseline (3695.304 us; speedup 1.0000x reference)
//
#include <hip/hip_runtime.h>
#include <math.h>

#define T_SEQ 1024
#define LH 125      // lstm hidden
#define G4 500      // 4*L gates

__device__ __forceinline__ float fsig(float x) {
    // overflow-safe sigmoid: exp(-x) -> inf => 0, -> 0 => 1
    return 1.f / (1.f + __expf(-x));
}
__device__ __forceinline__ float ftanh(float x) {
    // tanh(x) = 2*sigmoid(2x) - 1, overflow-safe at both ends
    float e = __expf(-2.f * x);
    return 2.f / (1.f + e) - 1.f;
}

// ---------------- embedding gather + concat: x[t] = [W_emb[wid[t]], P_emb[pid[t]]]
__global__ void k_embed(const int* __restrict__ wid, const int* __restrict__ pid,
                        const float* __restrict__ W, const float* __restrict__ P,
                        float* __restrict__ x) {
    int t = blockIdx.x;
    int k = threadIdx.x;               // 128 threads
    if (k < 100) {
        x[t * 125 + k] = W[wid[t] * 100 + k];
    } else if (k < 125) {
        x[t * 125 + k] = P[pid[t] * 25 + (k - 100)];
    }
}

// ---------------- input projection for both directions: pre[t][j] = b[j] + sum_k x[t][k]*Wih[j][k]
template <int K>
__global__ void k_preproj(const float* __restrict__ xin,
                          const float* __restrict__ Wf, const float* __restrict__ bf,
                          const float* __restrict__ Wb, const float* __restrict__ bb,
                          float* __restrict__ pf, float* __restrict__ pb) {
    __shared__ float xs[K];
    int t = blockIdx.x, j = threadIdx.x;   // block 512
    for (int k = j; k < K; k += 512) xs[k] = xin[t * K + k];
    __syncthreads();
    if (j < G4) {
        const float* wf = Wf + (long)j * K;
        const float* wb = Wb + (long)j * K;
        float af = bf[j], ab = bb[j];
        #pragma unroll 5
        for (int k = 0; k < K; ++k) {
            float xv = xs[k];
            af += wf[k] * xv;
            ab += wb[k] * xv;
        }
        pf[t * G4 + j] = af;
        pb[t * G4 + j] = ab;
    }
}

// ---------------- sequential LSTM scan, one block per direction
// blockIdx.x == 0 : forward  (writes cols [125,250))
// blockIdx.x == 1 : backward (writes cols [0,125))
__global__ void __launch_bounds__(512, 1)
k_scan(const float* __restrict__ pf, const float* __restrict__ Wf,
       const float* __restrict__ pb, const float* __restrict__ Wb,
       float* __restrict__ hout) {
    const int dir = blockIdx.x;
    const float* __restrict__ pre = dir ? pb : pf;
    const float* __restrict__ Whh = dir ? Wb : Wf;
    const int col0 = dir ? 0 : 125;

    __shared__ __align__(16) float h_lds[128];
    __shared__ float g_lds[G4];

    const int j = threadIdx.x;

    // per-thread Whh row in registers, padded to 128
    float w[128];
    if (j < G4) {
        #pragma unroll
        for (int k = 0; k < 125; ++k) w[k] = Whh[j * 125 + k];
        #pragma unroll
        for (int k = 125; k < 128; ++k) w[k] = 0.f;
    } else {
        #pragma unroll
        for (int k = 0; k < 128; ++k) w[k] = 0.f;
    }
    if (j < 128) h_lds[j] = 0.f;
    float c = 0.f;
    __syncthreads();

    const float4* __restrict__ h4 = reinterpret_cast<const float4*>(h_lds);

    for (int s = 0; s < T_SEQ; ++s) {
        const int t = dir ? (T_SEQ - 1 - s) : s;
        if (j < G4) {
            float pv = pre[t * G4 + j];
            float a0 = 0.f, a1 = 0.f, a2 = 0.f, a3 = 0.f;
            #pragma unroll
            for (int q = 0; q < 32; ++q) {
                float4 hv = h4[q];
                a0 += w[4 * q + 0] * hv.x;
                a1 += w[4 * q + 1] * hv.y;
                a2 += w[4 * q + 2] * hv.z;
                a3 += w[4 * q + 3] * hv.w;
            }
            g_lds[j] = pv + ((a0 + a1) + (a2 + a3));
        }
        __syncthreads();
        if (j < LH) {
            float iv = fsig(g_lds[j]);
            float fv = fsig(g_lds[125 + j]);
            float gv = ftanh(g_lds[250 + j]);
            float ov = fsig(g_lds[375 + j]);
            c = fv * c + iv * gv;
            float h = ov * ftanh(c);
            h_lds[j] = h;
            hout[t * 250 + col0 + j] = h;
        }
        __syncthreads();
    }
}

// ---------------- head' = h2 @ FOH + bias ; mod = h2 @ FOM
__global__ void k_headmod(const float* __restrict__ h2,
                          const float* __restrict__ FOH, const float* __restrict__ FOM,
                          const float* __restrict__ bias,
                          float* __restrict__ headp, float* __restrict__ modv) {
    __shared__ float hs[250];
    int t = blockIdx.x, tid = threadIdx.x;   // block 256
    for (int k = tid; k < 250; k += 256) hs[k] = h2[t * 250 + k];
    __syncthreads();
    if (tid < 100) {
        float a = 0.f;
        #pragma unroll 5
        for (int k = 0; k < 250; ++k) a += hs[k] * FOH[k * 100 + tid];
        headp[t * 100 + tid] = a + bias[tid];
    } else if (tid >= 128 && tid < 228) {
        int h = tid - 128;
        float a = 0.f;
        #pragma unroll 5
        for (int k = 0; k < 250; ++k) a += hs[k] * FOM[k * 100 + h];
        modv[t * 100 + h] = a;
    }
}

// ---------------- scores[i][j] = sum_h tanh(head'[i][h] + mod[j][h]) * outW[h]
__global__ void k_score(const float* __restrict__ headp, const float* __restrict__ modv,
                        const float* __restrict__ outw, float* __restrict__ out) {
    __shared__ float hh[16][100];
    __shared__ float mm[16][100];
    __shared__ float ow[100];
    const int bi = blockIdx.y, bj = blockIdx.x;
    const int tx = threadIdx.x, ty = threadIdx.y;   // 16x16
    const int tid = ty * 16 + tx;
    for (int q = tid; q < 1600; q += 256) {
        int r = q / 100, cidx = q % 100;
        hh[r][cidx] = headp[(bi * 16 + r) * 100 + cidx];
        mm[r][cidx] = modv[(bj * 16 + r) * 100 + cidx];
    }
    if (tid < 100) ow[tid] = outw[tid];
    __syncthreads();
    float acc = 0.f;
    #pragma unroll 4
    for (int h = 0; h < 100; ++h) {
        acc += ftanh(hh[ty][h] + mm[tx][h]) * ow[h];
    }
    out[(bi * 16 + ty) * 1024 + (bj * 16 + tx)] = acc;
}

extern "C" void kernel_launch(void* const* d_in, const int* in_sizes, int n_in,
                              void* d_out, int out_size, void* d_ws, size_t ws_size,
                              hipStream_t stream) {
    const int*   wid    = (const int*)d_in[0];
    const int*   pid    = (const int*)d_in[1];
    const float* W_emb  = (const float*)d_in[2];
    const float* P_emb  = (const float*)d_in[3];
    const float* Wih_f0 = (const float*)d_in[4];
    const float* Whh_f0 = (const float*)d_in[5];
    const float* b_f0   = (const float*)d_in[6];
    const float* Wih_b0 = (const float*)d_in[7];
    const float* Whh_b0 = (const float*)d_in[8];
    const float* b_b0   = (const float*)d_in[9];
    const float* Wih_f1 = (const float*)d_in[10];
    const float* Whh_f1 = (const float*)d_in[11];
    const float* b_f1   = (const float*)d_in[12];
    const float* Wih_b1 = (const float*)d_in[13];
    const float* Whh_b1 = (const float*)d_in[14];
    const float* b_b1   = (const float*)d_in[15];
    const float* FOH    = (const float*)d_in[16];
    const float* FOM    = (const float*)d_in[17];
    const float* hidB   = (const float*)d_in[18];
    const float* outW   = (const float*)d_in[19];
    float* out = (float*)d_out;
    float* ws  = (float*)d_ws;

    // workspace layout (floats)
    float* x     = ws;                  // 1024*125  = 128000
    float* pf    = x     + 128000;      // 1024*500  = 512000
    float* pb    = pf    + 512000;      // 512000
    float* h1    = pb    + 512000;      // 1024*250  = 256000
    float* h2    = h1    + 256000;      // 256000
    float* headp = h2    + 256000;      // 1024*100  = 102400
    float* modv  = headp + 102400;      // 102400
    // total ~7.5 MB

    k_embed<<<T_SEQ, 128, 0, stream>>>(wid, pid, W_emb, P_emb, x);

    // layer 1
    k_preproj<125><<<T_SEQ, 512, 0, stream>>>(x, Wih_f0, b_f0, Wih_b0, b_b0, pf, pb);
    k_scan<<<2, 512, 0, stream>>>(pf, Whh_f0, pb, Whh_b0, h1);

    // layer 2 (input = h1, K=250; recurrent Whh still [500,125])
    k_preproj<250><<<T_SEQ, 512, 0, stream>>>(h1, Wih_f1, b_f1, Wih_b1, b_b1, pf, pb);
    k_scan<<<2, 512, 0, stream>>>(pf, Whh_f1, pb, Whh_b1, h2);

    // arc scorer
    k_headmod<<<T_SEQ, 256, 0, stream>>>(h2, FOH, FOM, hidB, headp, modv);
    dim3 gs(64, 64), bs(16, 16);
    k_score<<<gs, bs, 0, stream>>>(headp, modv, outW, out);
}

// Round 2
// 2512.784 us; speedup vs baseline: 1.4706x; 1.4706x over previous
//
#include <hip/hip_runtime.h>
#include <math.h>

#define T_SEQ 1024
#define LH 125      // lstm hidden
#define G4 500      // 4*L gates

__device__ __forceinline__ float fsig(float x) {
    return 1.f / (1.f + __expf(-x));
}
__device__ __forceinline__ float ftanh(float x) {
    float e = __expf(-2.f * x);
    return 2.f / (1.f + e) - 1.f;
}

// DPP quad-perm cross-lane adds: xor1 = [1,0,3,2] = 0xB1, xor2 = [2,3,0,1] = 0x4E
__device__ __forceinline__ float dpp_xor1_add(float x) {
    int xi = __float_as_int(x);
    int yi = __builtin_amdgcn_update_dpp(xi, xi, 0xB1, 0xF, 0xF, true);
    return x + __int_as_float(yi);
}
__device__ __forceinline__ float dpp_xor2_add(float x) {
    int xi = __float_as_int(x);
    int yi = __builtin_amdgcn_update_dpp(xi, xi, 0x4E, 0xF, 0xF, true);
    return x + __int_as_float(yi);
}

// ---------------- embedding gather + concat
__global__ void k_embed(const int* __restrict__ wid, const int* __restrict__ pid,
                        const float* __restrict__ W, const float* __restrict__ P,
                        float* __restrict__ x) {
    int t = blockIdx.x;
    int k = threadIdx.x;               // 128 threads
    if (k < 100) {
        x[t * 125 + k] = W[wid[t] * 100 + k];
    } else if (k < 125) {
        x[t * 125 + k] = P[pid[t] * 25 + (k - 100)];
    }
}

// ---------------- input projection for both directions
template <int K>
__global__ void k_preproj(const float* __restrict__ xin,
                          const float* __restrict__ Wf, const float* __restrict__ bf,
                          const float* __restrict__ Wb, const float* __restrict__ bb,
                          float* __restrict__ pf, float* __restrict__ pb) {
    __shared__ float xs[K];
    int t = blockIdx.x, j = threadIdx.x;   // block 512
    for (int k = j; k < K; k += 512) xs[k] = xin[t * K + k];
    __syncthreads();
    if (j < G4) {
        const float* wf = Wf + (long)j * K;
        const float* wb = Wb + (long)j * K;
        float af = bf[j], ab = bb[j];
        #pragma unroll 5
        for (int k = 0; k < K; ++k) {
            float xv = xs[k];
            af += wf[k] * xv;
            ab += wb[k] * xv;
        }
        pf[t * G4 + j] = af;
        pb[t * G4 + j] = ab;
    }
}

// ---------------- sequential LSTM scan, one 1024-thread block per direction
// Layout: kp = tid&3 owns k in [kp*32, kp*32+32); jg = tid>>2 owns outputs {jg, 256+jg}
// h_lds: 4 padded regions of 36 floats (region kp holds h[kp*32 .. kp*32+31])
__global__ void __launch_bounds__(1024, 4)
k_scan(const float* __restrict__ pf, const float* __restrict__ Wf,
       const float* __restrict__ pb, const float* __restrict__ Wb,
       float* __restrict__ hout) {
    const int dir = blockIdx.x;
    const float* __restrict__ pre = dir ? pb : pf;
    const float* __restrict__ Whh = dir ? Wb : Wf;
    const int col0 = dir ? 0 : 125;

    __shared__ __align__(16) float h_lds[4 * 36];   // 144 floats, padded regions
    __shared__ float g_lds[G4];

    const int tid = threadIdx.x;
    const int kp  = tid & 3;
    const int jg  = tid >> 2;          // 0..255
    const int o0  = jg;                // pass-0 output (< 500 always)
    const int o1  = 256 + jg;          // pass-1 output (valid if < 500)
    const bool v1 = (o1 < G4);

    // per-lane weights: 2 passes x 32 k values = 64 floats (registers)
    float w0[32], w1[32];
    #pragma unroll
    for (int m = 0; m < 32; ++m) {
        int k = kp * 32 + m;
        w0[m] = (k < LH) ? Whh[o0 * LH + k] : 0.f;
        w1[m] = (v1 && k < LH) ? Whh[o1 * LH + k] : 0.f;
    }

    // zero-init h and pads
    for (int q = tid; q < 4 * 36; q += 1024) h_lds[q] = 0.f;
    float c = 0.f;
    __syncthreads();

    const float* hbase = &h_lds[kp * 36];

    for (int s = 0; s < T_SEQ; ++s) {
        const int t = dir ? (T_SEQ - 1 - s) : s;

        // issue pre loads early (L2 latency hides under LDS reads + MACs)
        float acc0 = 0.f, acc1 = 0.f;
        if (kp == 0) {
            acc0 = pre[t * G4 + o0];
            if (v1) acc1 = pre[t * G4 + o1];
        }

        #pragma unroll
        for (int q = 0; q < 8; ++q) {
            float4 hv = *reinterpret_cast<const float4*>(hbase + q * 4);
            acc0 += w0[q * 4 + 0] * hv.x + w0[q * 4 + 1] * hv.y
                  + w0[q * 4 + 2] * hv.z + w0[q * 4 + 3] * hv.w;
            acc1 += w1[q * 4 + 0] * hv.x + w1[q * 4 + 1] * hv.y
                  + w1[q * 4 + 2] * hv.z + w1[q * 4 + 3] * hv.w;
        }

        // reduce over the 4 k-parts (quad lanes) with DPP
        acc0 = dpp_xor2_add(dpp_xor1_add(acc0));
        acc1 = dpp_xor2_add(dpp_xor1_add(acc1));

        if (kp == 0) {
            g_lds[o0] = acc0;
            if (v1) g_lds[o1] = acc1;
        }
        __syncthreads();

        if (tid < LH) {
            float iv = fsig(g_lds[tid]);
            float fv = fsig(g_lds[125 + tid]);
            float gv = ftanh(g_lds[250 + tid]);
            float ov = fsig(g_lds[375 + tid]);
            c = fv * c + iv * gv;
            float h = ov * ftanh(c);
            h_lds[(tid >> 5) * 36 + (tid & 31)] = h;
            hout[t * 250 + col0 + tid] = h;
        }
        __syncthreads();
    }
}

// ---------------- head' = h2 @ FOH + bias ; mod = h2 @ FOM
__global__ void k_headmod(const float* __restrict__ h2,
                          const float* __restrict__ FOH, const float* __restrict__ FOM,
                          const float* __restrict__ bias,
                          float* __restrict__ headp, float* __restrict__ modv) {
    __shared__ float hs[250];
    int t = blockIdx.x, tid = threadIdx.x;   // block 256
    for (int k = tid; k < 250; k += 256) hs[k] = h2[t * 250 + k];
    __syncthreads();
    if (tid < 100) {
        float a = 0.f;
        #pragma unroll 5
        for (int k = 0; k < 250; ++k) a += hs[k] * FOH[k * 100 + tid];
        headp[t * 100 + tid] = a + bias[tid];
    } else if (tid >= 128 && tid < 228) {
        int h = tid - 128;
        float a = 0.f;
        #pragma unroll 5
        for (int k = 0; k < 250; ++k) a += hs[k] * FOM[k * 100 + h];
        modv[t * 100 + h] = a;
    }
}

// ---------------- scores[i][j] = sum_h tanh(head'[i][h] + mod[j][h]) * outW[h]
__global__ void k_score(const float* __restrict__ headp, const float* __restrict__ modv,
                        const float* __restrict__ outw, float* __restrict__ out) {
    __shared__ float hh[16][100];
    __shared__ float mm[16][100];
    __shared__ float ow[100];
    const int bi = blockIdx.y, bj = blockIdx.x;
    const int tx = threadIdx.x, ty = threadIdx.y;   // 16x16
    const int tid = ty * 16 + tx;
    for (int q = tid; q < 1600; q += 256) {
        int r = q / 100, cidx = q % 100;
        hh[r][cidx] = headp[(bi * 16 + r) * 100 + cidx];
        mm[r][cidx] = modv[(bj * 16 + r) * 100 + cidx];
    }
    if (tid < 100) ow[tid] = outw[tid];
    __syncthreads();
    float acc = 0.f;
    #pragma unroll 4
    for (int h = 0; h < 100; ++h) {
        acc += ftanh(hh[ty][h] + mm[tx][h]) * ow[h];
    }
    out[(bi * 16 + ty) * 1024 + (bj * 16 + tx)] = acc;
}

extern "C" void kernel_launch(void* const* d_in, const int* in_sizes, int n_in,
                              void* d_out, int out_size, void* d_ws, size_t ws_size,
                              hipStream_t stream) {
    const int*   wid    = (const int*)d_in[0];
    const int*   pid    = (const int*)d_in[1];
    const float* W_emb  = (const float*)d_in[2];
    const float* P_emb  = (const float*)d_in[3];
    const float* Wih_f0 = (const float*)d_in[4];
    const float* Whh_f0 = (const float*)d_in[5];
    const float* b_f0   = (const float*)d_in[6];
    const float* Wih_b0 = (const float*)d_in[7];
    const float* Whh_b0 = (const float*)d_in[8];
    const float* b_b0   = (const float*)d_in[9];
    const float* Wih_f1 = (const float*)d_in[10];
    const float* Whh_f1 = (const float*)d_in[11];
    const float* b_f1   = (const float*)d_in[12];
    const float* Wih_b1 = (const float*)d_in[13];
    const float* Whh_b1 = (const float*)d_in[14];
    const float* b_b1   = (const float*)d_in[15];
    const float* FOH    = (const float*)d_in[16];
    const float* FOM    = (const float*)d_in[17];
    const float* hidB   = (const float*)d_in[18];
    const float* outW   = (const float*)d_in[19];
    float* out = (float*)d_out;
    float* ws  = (float*)d_ws;

    float* x     = ws;                  // 1024*125
    float* pf    = x     + 128000;      // 1024*500
    float* pb    = pf    + 512000;
    float* h1    = pb    + 512000;      // 1024*250
    float* h2    = h1    + 256000;
    float* headp = h2    + 256000;      // 1024*100
    float* modv  = headp + 102400;

    k_embed<<<T_SEQ, 128, 0, stream>>>(wid, pid, W_emb, P_emb, x);

    k_preproj<125><<<T_SEQ, 512, 0, stream>>>(x, Wih_f0, b_f0, Wih_b0, b_b0, pf, pb);
    k_scan<<<2, 1024, 0, stream>>>(pf, Whh_f0, pb, Whh_b0, h1);

    k_preproj<250><<<T_SEQ, 512, 0, stream>>>(h1, Wih_f1, b_f1, Wih_b1, b_b1, pf, pb);
    k_scan<<<2, 1024, 0, stream>>>(pf, Whh_f1, pb, Whh_b1, h2);

    k_headmod<<<T_SEQ, 256, 0, stream>>>(h2, FOH, FOM, hidB, headp, modv);
    dim3 gs(64, 64), bs(16, 16);
    k_score<<<gs, bs, 0, stream>>>(headp, modv, outW, out);
}

// Round 3
// 1965.420 us; speedup vs baseline: 1.8802x; 1.2785x over previous
//
#include <hip/hip_runtime.h>
#include <math.h>

#define T_SEQ 1024
#define LH 125      // lstm hidden
#define G4 500      // 4*L gates

typedef _Float16 h16 __attribute__((ext_vector_type(16)));
typedef _Float16 h2  __attribute__((ext_vector_type(2)));

__device__ __forceinline__ float fsig(float x) {
    return __builtin_amdgcn_rcpf(1.f + __expf(-x));
}
__device__ __forceinline__ float ftanh(float x) {
    float e = __expf(-2.f * x);
    return 2.f * __builtin_amdgcn_rcpf(1.f + e) - 1.f;
}

// DPP cross-lane adds within 8-lane groups: xor1 (quad 0xB1), xor2 (quad 0x4E),
// then row_half_mirror (0x141, lane^7) which after xor1+xor2 adds the other quad's sum.
__device__ __forceinline__ float dpp_xor1_add(float x) {
    int xi = __float_as_int(x);
    int yi = __builtin_amdgcn_update_dpp(xi, xi, 0xB1, 0xF, 0xF, true);
    return x + __int_as_float(yi);
}
__device__ __forceinline__ float dpp_xor2_add(float x) {
    int xi = __float_as_int(x);
    int yi = __builtin_amdgcn_update_dpp(xi, xi, 0x4E, 0xF, 0xF, true);
    return x + __int_as_float(yi);
}
__device__ __forceinline__ float dpp_hmirror_add(float x) {
    int xi = __float_as_int(x);
    int yi = __builtin_amdgcn_update_dpp(xi, xi, 0x141, 0xF, 0xF, true);
    return x + __int_as_float(yi);
}
__device__ __forceinline__ float red8(float x) {
    return dpp_hmirror_add(dpp_xor2_add(dpp_xor1_add(x)));
}

// Load up to 16 f32 weights -> f16 vector, all indices compile-time constants (stays SSA).
__device__ __forceinline__ h16 load_w16(const float* __restrict__ wp, int nvalid) {
    h16 r;
#define SETW(i) r[i] = ((i) < nvalid) ? (_Float16)wp[i] : (_Float16)0.f;
    SETW(0) SETW(1) SETW(2) SETW(3) SETW(4) SETW(5) SETW(6) SETW(7)
    SETW(8) SETW(9) SETW(10) SETW(11) SETW(12) SETW(13) SETW(14) SETW(15)
#undef SETW
    return r;
}

// 16-term f16 dot via 8x v_dot2_f32_f16, f32 accumulate.
__device__ __forceinline__ float mac16(h16 w, h16 h, float acc) {
#define DOT(p) acc = __builtin_amdgcn_fdot2( \
        __builtin_shufflevector(w, w, 2*(p), 2*(p)+1), \
        __builtin_shufflevector(h, h, 2*(p), 2*(p)+1), acc, false);
    DOT(0) DOT(1) DOT(2) DOT(3) DOT(4) DOT(5) DOT(6) DOT(7)
#undef DOT
    return acc;
}

// ---------------- layer-0 input projection, embedding gather fused, 4 timesteps/block
__global__ void k_preproj0(const int* __restrict__ wid, const int* __restrict__ pid,
                           const float* __restrict__ W_emb, const float* __restrict__ P_emb,
                           const float* __restrict__ Wf, const float* __restrict__ bf,
                           const float* __restrict__ Wb, const float* __restrict__ bb,
                           float* __restrict__ pf, float* __restrict__ pb) {
    __shared__ float xs[4][128];
    const int t0 = blockIdx.x * 4;
    const int tid = threadIdx.x;   // 512
    for (int tt = 0; tt < 4; ++tt) {
        int t = t0 + tt;
        for (int k = tid; k < 125; k += 512)
            xs[tt][k] = (k < 100) ? W_emb[wid[t] * 100 + k] : P_emb[pid[t] * 25 + (k - 100)];
    }
    __syncthreads();
    const int j = tid;
    if (j < G4) {
        const float* wf = Wf + j * 125;
        const float* wb = Wb + j * 125;
        float af0 = bf[j], af1 = af0, af2 = af0, af3 = af0;
        float ab0 = bb[j], ab1 = ab0, ab2 = ab0, ab3 = ab0;
        #pragma unroll 5
        for (int k = 0; k < 125; ++k) {
            float wfk = wf[k], wbk = wb[k];
            af0 += wfk * xs[0][k]; af1 += wfk * xs[1][k];
            af2 += wfk * xs[2][k]; af3 += wfk * xs[3][k];
            ab0 += wbk * xs[0][k]; ab1 += wbk * xs[1][k];
            ab2 += wbk * xs[2][k]; ab3 += wbk * xs[3][k];
        }
        pf[(t0 + 0) * G4 + j] = af0; pf[(t0 + 1) * G4 + j] = af1;
        pf[(t0 + 2) * G4 + j] = af2; pf[(t0 + 3) * G4 + j] = af3;
        pb[(t0 + 0) * G4 + j] = ab0; pb[(t0 + 1) * G4 + j] = ab1;
        pb[(t0 + 2) * G4 + j] = ab2; pb[(t0 + 3) * G4 + j] = ab3;
    }
}

// ---------------- layer-1 input projection (input = h1, K=250), 4 timesteps/block
__global__ void k_preproj1(const float* __restrict__ h1,
                           const float* __restrict__ Wf, const float* __restrict__ bf,
                           const float* __restrict__ Wb, const float* __restrict__ bb,
                           float* __restrict__ pf, float* __restrict__ pb) {
    __shared__ float xs[4][256];
    const int t0 = blockIdx.x * 4;
    const int tid = threadIdx.x;   // 512
    for (int tt = 0; tt < 4; ++tt) {
        int t = t0 + tt;
        for (int k = tid; k < 250; k += 512) xs[tt][k] = h1[t * 250 + k];
    }
    __syncthreads();
    const int j = tid;
    if (j < G4) {
        const float* wf = Wf + j * 250;
        const float* wb = Wb + j * 250;
        float af0 = bf[j], af1 = af0, af2 = af0, af3 = af0;
        float ab0 = bb[j], ab1 = ab0, ab2 = ab0, ab3 = ab0;
        #pragma unroll 5
        for (int k = 0; k < 250; ++k) {
            float wfk = wf[k], wbk = wb[k];
            af0 += wfk * xs[0][k]; af1 += wfk * xs[1][k];
            af2 += wfk * xs[2][k]; af3 += wfk * xs[3][k];
            ab0 += wbk * xs[0][k]; ab1 += wbk * xs[1][k];
            ab2 += wbk * xs[2][k]; ab3 += wbk * xs[3][k];
        }
        pf[(t0 + 0) * G4 + j] = af0; pf[(t0 + 1) * G4 + j] = af1;
        pf[(t0 + 2) * G4 + j] = af2; pf[(t0 + 3) * G4 + j] = af3;
        pb[(t0 + 0) * G4 + j] = ab0; pb[(t0 + 1) * G4 + j] = ab1;
        pb[(t0 + 2) * G4 + j] = ab2; pb[(t0 + 3) * G4 + j] = ab3;
    }
}

// ---------------- sequential LSTM scan, one 512-thread block per direction
// kp = tid&7 owns k-slice [16kp,16kp+16); jg = tid>>3 in [0,64)
// lane computes partial dots for outputs {64m+jg : m=0..7}; DPP-reduce over the 8 kp lanes.
// lane then owns output o_self = 64*kp + jg: adds pre, applies gate nonlinearity, writes g_lds.
// h stored f16 in LDS, 8 regions of 24 halves (48B stride -> conflict-free b128 reads).
__global__ void __launch_bounds__(512, 2)
k_scan(const float* __restrict__ pf, const float* __restrict__ Wf,
       const float* __restrict__ pb, const float* __restrict__ Wb,
       float* __restrict__ hout) {
    const int dir = blockIdx.x;
    const float* __restrict__ pre = dir ? pb : pf;
    const float* __restrict__ Whh = dir ? Wb : Wf;
    const int col0 = dir ? 0 : 125;

    __shared__ __align__(16) _Float16 h_lds[8 * 24];   // 16 used + 8 pad per region
    __shared__ float g_lds[G4];

    const int tid = threadIdx.x;
    const int kp  = tid & 7;
    const int jg  = tid >> 3;
    const int kbase = kp * 16;
    const int o_self = 64 * kp + jg;
    const bool vself = (o_self < G4);

    // valid k count for this k-slice (kp=7 -> 13)
    int nvalid = LH - kbase; nvalid = nvalid < 0 ? 0 : (nvalid > 16 ? 16 : nvalid);

    // weights: 8 outputs x 16 k, f16, named ext-vectors (register-resident)
#define LW(m) h16 w##m; { int o = 64*(m) + jg; \
        const float* wp = Whh + (o < G4 ? o : (G4 - 1)) * LH + kbase; \
        w##m = load_w16(wp, (o < G4) ? nvalid : 0); }
    LW(0) LW(1) LW(2) LW(3) LW(4) LW(5) LW(6) LW(7)
#undef LW

    // per-lane gate nonlinearity constants: sigmoid for i,f,o ; tanh for g
    const bool is_sig = (o_self < 250) || (o_self >= 375);
    const float Ac = is_sig ? 1.f : 2.f;
    const float Bc = is_sig ? -1.f : -2.f;
    const float Cc = is_sig ? 0.f : -1.f;

    for (int q = tid; q < 8 * 24; q += 512) h_lds[q] = (_Float16)0.f;
    float c = 0.f;
    __syncthreads();

    const h16* __restrict__ hvp = reinterpret_cast<const h16*>(&h_lds[kp * 24]);

    // pre double-buffer: pv holds step s's value, loaded one step ahead
    int t_first = dir ? (T_SEQ - 1) : 0;
    float pv = vself ? pre[t_first * G4 + o_self] : 0.f;

    for (int s = 0; s < T_SEQ; ++s) {
        const int t  = dir ? (T_SEQ - 1 - s) : s;
        const int sn = (s + 1 < T_SEQ) ? s + 1 : s;
        const int tn = dir ? (T_SEQ - 1 - sn) : sn;
        float pvn = vself ? pre[tn * G4 + o_self] : 0.f;   // prefetch next step

        h16 hv = *hvp;
        float a0 = mac16(w0, hv, 0.f);
        float a1 = mac16(w1, hv, 0.f);
        float a2 = mac16(w2, hv, 0.f);
        float a3 = mac16(w3, hv, 0.f);
        float a4 = mac16(w4, hv, 0.f);
        float a5 = mac16(w5, hv, 0.f);
        float a6 = mac16(w6, hv, 0.f);
        float a7 = mac16(w7, hv, 0.f);
        a0 = red8(a0); a1 = red8(a1); a2 = red8(a2); a3 = red8(a3);
        a4 = red8(a4); a5 = red8(a5); a6 = red8(a6); a7 = red8(a7);

        float gsum = (kp == 0) ? a0 : (kp == 1) ? a1 : (kp == 2) ? a2 : (kp == 3) ? a3
                   : (kp == 4) ? a4 : (kp == 5) ? a5 : (kp == 6) ? a6 : a7;
        // gate nonlinearity in-lane: sigmoid or tanh via A*rcp(1+exp(B*x))+C
        float gv = Ac * __builtin_amdgcn_rcpf(1.f + __expf(Bc * (gsum + pv))) + Cc;
        if (vself) g_lds[o_self] = gv;
        __syncthreads();

        if (tid < LH) {
            float iv = g_lds[tid];
            float fv = g_lds[125 + tid];
            float gg = g_lds[250 + tid];
            float ov = g_lds[375 + tid];
            c = fv * c + iv * gg;
            float e  = __expf(-2.f * c);
            float th = 2.f * __builtin_amdgcn_rcpf(1.f + e) - 1.f;
            float h  = ov * th;
            h_lds[(tid >> 4) * 24 + (tid & 15)] = (_Float16)h;
            hout[t * 250 + col0 + tid] = h;
        }
        __syncthreads();
        pv = pvn;
    }
}

// ---------------- head' = h2 @ FOH + bias ; mod = h2 @ FOM
__global__ void k_headmod(const float* __restrict__ h2,
                          const float* __restrict__ FOH, const float* __restrict__ FOM,
                          const float* __restrict__ bias,
                          float* __restrict__ headp, float* __restrict__ modv) {
    __shared__ float hs[250];
    int t = blockIdx.x, tid = threadIdx.x;   // block 256
    for (int k = tid; k < 250; k += 256) hs[k] = h2[t * 250 + k];
    __syncthreads();
    if (tid < 100) {
        float a = 0.f;
        #pragma unroll 5
        for (int k = 0; k < 250; ++k) a += hs[k] * FOH[k * 100 + tid];
        headp[t * 100 + tid] = a + bias[tid];
    } else if (tid >= 128 && tid < 228) {
        int h = tid - 128;
        float a = 0.f;
        #pragma unroll 5
        for (int k = 0; k < 250; ++k) a += hs[k] * FOM[k * 100 + h];
        modv[t * 100 + h] = a;
    }
}

// ---------------- scores[i][j] = sum_h tanh(head'[i][h] + mod[j][h]) * outW[h]
__global__ void k_score(const float* __restrict__ headp, const float* __restrict__ modv,
                        const float* __restrict__ outw, float* __restrict__ out) {
    __shared__ float hh[16][100];
    __shared__ float mm[16][100];
    __shared__ float ow[100];
    const int bi = blockIdx.y, bj = blockIdx.x;
    const int tx = threadIdx.x, ty = threadIdx.y;   // 16x16
    const int tid = ty * 16 + tx;
    for (int q = tid; q < 1600; q += 256) {
        int r = q / 100, cidx = q % 100;
        hh[r][cidx] = headp[(bi * 16 + r) * 100 + cidx];
        mm[r][cidx] = modv[(bj * 16 + r) * 100 + cidx];
    }
    if (tid < 100) ow[tid] = outw[tid];
    __syncthreads();
    float acc = 0.f;
    #pragma unroll 4
    for (int h = 0; h < 100; ++h) {
        acc += ftanh(hh[ty][h] + mm[tx][h]) * ow[h];
    }
    out[(bi * 16 + ty) * 1024 + (bj * 16 + tx)] = acc;
}

extern "C" void kernel_launch(void* const* d_in, const int* in_sizes, int n_in,
                              void* d_out, int out_size, void* d_ws, size_t ws_size,
                              hipStream_t stream) {
    const int*   wid    = (const int*)d_in[0];
    const int*   pid    = (const int*)d_in[1];
    const float* W_emb  = (const float*)d_in[2];
    const float* P_emb  = (const float*)d_in[3];
    const float* Wih_f0 = (const float*)d_in[4];
    const float* Whh_f0 = (const float*)d_in[5];
    const float* b_f0   = (const float*)d_in[6];
    const float* Wih_b0 = (const float*)d_in[7];
    const float* Whh_b0 = (const float*)d_in[8];
    const float* b_b0   = (const float*)d_in[9];
    const float* Wih_f1 = (const float*)d_in[10];
    const float* Whh_f1 = (const float*)d_in[11];
    const float* b_f1   = (const float*)d_in[12];
    const float* Wih_b1 = (const float*)d_in[13];
    const float* Whh_b1 = (const float*)d_in[14];
    const float* b_b1   = (const float*)d_in[15];
    const float* FOH    = (const float*)d_in[16];
    const float* FOM    = (const float*)d_in[17];
    const float* hidB   = (const float*)d_in[18];
    const float* outW   = (const float*)d_in[19];
    float* out = (float*)d_out;
    float* ws  = (float*)d_ws;

    float* pf    = ws;                  // 1024*500
    float* pb    = pf    + 512000;
    float* h1    = pb    + 512000;      // 1024*250
    float* h2    = h1    + 256000;
    float* headp = h2    + 256000;      // 1024*100
    float* modv  = headp + 102400;

    k_preproj0<<<256, 512, 0, stream>>>(wid, pid, W_emb, P_emb,
                                        Wih_f0, b_f0, Wih_b0, b_b0, pf, pb);
    k_scan<<<2, 512, 0, stream>>>(pf, Whh_f0, pb, Whh_b0, h1);

    k_preproj1<<<256, 512, 0, stream>>>(h1, Wih_f1, b_f1, Wih_b1, b_b1, pf, pb);
    k_scan<<<2, 512, 0, stream>>>(pf, Whh_f1, pb, Whh_b1, h2);

    k_headmod<<<T_SEQ, 256, 0, stream>>>(h2, FOH, FOM, hidB, headp, modv);
    dim3 gs(64, 64), bs(16, 16);
    k_score<<<gs, bs, 0, stream>>>(headp, modv, outW, out);
}

// Round 4
// 1383.097 us; speedup vs baseline: 2.6718x; 1.4210x over previous
//
#include <hip/hip_runtime.h>
#include <math.h>

#define T_SEQ 1024
#define LH 125      // lstm hidden
#define G4 500      // 4*L gates

typedef _Float16 h16 __attribute__((ext_vector_type(16)));

__device__ __forceinline__ float fsig(float x) {
    return __builtin_amdgcn_rcpf(1.f + __expf(-x));
}
__device__ __forceinline__ float ftanh(float x) {
    float e = __expf(-2.f * x);
    return 2.f * __builtin_amdgcn_rcpf(1.f + e) - 1.f;
}

// DPP quad-perm cross-lane adds: after xor1+xor2 every lane of the quad has the 4-lane sum
__device__ __forceinline__ float dpp_xor1_add(float x) {
    int xi = __float_as_int(x);
    int yi = __builtin_amdgcn_update_dpp(xi, xi, 0xB1, 0xF, 0xF, true);
    return x + __int_as_float(yi);
}
__device__ __forceinline__ float dpp_xor2_add(float x) {
    int xi = __float_as_int(x);
    int yi = __builtin_amdgcn_update_dpp(xi, xi, 0x4E, 0xF, 0xF, true);
    return x + __int_as_float(yi);
}
__device__ __forceinline__ float red4(float x) {
    return dpp_xor2_add(dpp_xor1_add(x));
}

// Load up to 16 f32 weights -> f16 vector, compile-time indices only (stays SSA)
__device__ __forceinline__ h16 load_w16(const float* __restrict__ wp, int nvalid) {
    h16 r;
#define SETW(i) r[i] = ((i) < nvalid) ? (_Float16)wp[i] : (_Float16)0.f;
    SETW(0) SETW(1) SETW(2) SETW(3) SETW(4) SETW(5) SETW(6) SETW(7)
    SETW(8) SETW(9) SETW(10) SETW(11) SETW(12) SETW(13) SETW(14) SETW(15)
#undef SETW
    return r;
}

// 16-term f16 dot via 8x v_dot2_f32_f16, f32 accumulate
__device__ __forceinline__ float mac16(h16 w, h16 h, float acc) {
#define DOT(p) acc = __builtin_amdgcn_fdot2( \
        __builtin_shufflevector(w, w, 2*(p), 2*(p)+1), \
        __builtin_shufflevector(h, h, 2*(p), 2*(p)+1), acc, false);
    DOT(0) DOT(1) DOT(2) DOT(3) DOT(4) DOT(5) DOT(6) DOT(7)
#undef DOT
    return acc;
}

// ---------------- layer-0 input projection, embedding fused, 4 timesteps/block
// Stores pre in interleaved layout: pre[t][unit][gate] (gate: 0=i,1=f,2=g,3=o)
__global__ void k_preproj0(const int* __restrict__ wid, const int* __restrict__ pid,
                           const float* __restrict__ W_emb, const float* __restrict__ P_emb,
                           const float* __restrict__ Wf, const float* __restrict__ bf,
                           const float* __restrict__ Wb, const float* __restrict__ bb,
                           float* __restrict__ pf, float* __restrict__ pb) {
    __shared__ float xs[4][128];
    const int t0 = blockIdx.x * 4;
    const int tid = threadIdx.x;   // 512
    for (int tt = 0; tt < 4; ++tt) {
        int t = t0 + tt;
        for (int k = tid; k < 125; k += 512)
            xs[tt][k] = (k < 100) ? W_emb[wid[t] * 100 + k] : P_emb[pid[t] * 25 + (k - 100)];
    }
    __syncthreads();
    const int j = tid;
    if (j < G4) {
        const float* wf = Wf + j * 125;
        const float* wb = Wb + j * 125;
        float af0 = bf[j], af1 = af0, af2 = af0, af3 = af0;
        float ab0 = bb[j], ab1 = ab0, ab2 = ab0, ab3 = ab0;
        #pragma unroll 5
        for (int k = 0; k < 125; ++k) {
            float wfk = wf[k], wbk = wb[k];
            af0 += wfk * xs[0][k]; af1 += wfk * xs[1][k];
            af2 += wfk * xs[2][k]; af3 += wfk * xs[3][k];
            ab0 += wbk * xs[0][k]; ab1 += wbk * xs[1][k];
            ab2 += wbk * xs[2][k]; ab3 += wbk * xs[3][k];
        }
        int g = j / 125, u = j - g * 125;
        int off = u * 4 + g;
        pf[(t0 + 0) * G4 + off] = af0; pf[(t0 + 1) * G4 + off] = af1;
        pf[(t0 + 2) * G4 + off] = af2; pf[(t0 + 3) * G4 + off] = af3;
        pb[(t0 + 0) * G4 + off] = ab0; pb[(t0 + 1) * G4 + off] = ab1;
        pb[(t0 + 2) * G4 + off] = ab2; pb[(t0 + 3) * G4 + off] = ab3;
    }
}

// ---------------- layer-1 input projection (input = h1, K=250), interleaved store
__global__ void k_preproj1(const float* __restrict__ h1,
                           const float* __restrict__ Wf, const float* __restrict__ bf,
                           const float* __restrict__ Wb, const float* __restrict__ bb,
                           float* __restrict__ pf, float* __restrict__ pb) {
    __shared__ float xs[4][256];
    const int t0 = blockIdx.x * 4;
    const int tid = threadIdx.x;   // 512
    for (int tt = 0; tt < 4; ++tt) {
        int t = t0 + tt;
        for (int k = tid; k < 250; k += 512) xs[tt][k] = h1[t * 250 + k];
    }
    __syncthreads();
    const int j = tid;
    if (j < G4) {
        const float* wf = Wf + j * 250;
        const float* wb = Wb + j * 250;
        float af0 = bf[j], af1 = af0, af2 = af0, af3 = af0;
        float ab0 = bb[j], ab1 = ab0, ab2 = ab0, ab3 = ab0;
        #pragma unroll 5
        for (int k = 0; k < 250; ++k) {
            float wfk = wf[k], wbk = wb[k];
            af0 += wfk * xs[0][k]; af1 += wfk * xs[1][k];
            af2 += wfk * xs[2][k]; af3 += wfk * xs[3][k];
            ab0 += wbk * xs[0][k]; ab1 += wbk * xs[1][k];
            ab2 += wbk * xs[2][k]; ab3 += wbk * xs[3][k];
        }
        int g = j / 125, u = j - g * 125;
        int off = u * 4 + g;
        pf[(t0 + 0) * G4 + off] = af0; pf[(t0 + 1) * G4 + off] = af1;
        pf[(t0 + 2) * G4 + off] = af2; pf[(t0 + 3) * G4 + off] = af3;
        pb[(t0 + 0) * G4 + off] = ab0; pb[(t0 + 1) * G4 + off] = ab1;
        pb[(t0 + 2) * G4 + off] = ab2; pb[(t0 + 3) * G4 + off] = ab3;
    }
}

// ---------------- sequential LSTM scan, one 512-thread block per direction
// jg = tid>>2 owns hidden unit jg (all 4 gate rows); kp = tid&3 owns k-slice [32kp, 32kp+32)
// Quad DPP reduce -> every quad lane has all 4 gate sums -> in-lane nonlinearity + c/h update
// (redundant x4, deterministic). h in f16 LDS, double-buffered, 4 regions x 48-half stride.
// One barrier per step.
__global__ void __launch_bounds__(512, 2)
k_scan(const float* __restrict__ pf, const float* __restrict__ Wf,
       const float* __restrict__ pb, const float* __restrict__ Wb,
       float* __restrict__ hout) {
    const int dir = blockIdx.x;
    const float* __restrict__ pre = dir ? pb : pf;   // [T][125][4]
    const float* __restrict__ Whh = dir ? Wb : Wf;
    const int col0 = dir ? 0 : 125;

    __shared__ __align__(32) _Float16 h_lds[2 * 4 * 48];  // 2 buf x 4 regions x (32 used + 16 pad)

    const int tid = threadIdx.x;
    const int kp  = tid & 3;
    const int jg  = tid >> 2;      // 0..127
    const int kbase = kp * 32;
    const bool vj = (jg < LH);
    const int u = vj ? jg : (LH - 1);

    // valid k counts for the two 16-wide sub-slices
    int nv0 = LH - kbase;       nv0 = nv0 < 0 ? 0 : (nv0 > 16 ? 16 : nv0);
    int nv1 = LH - kbase - 16;  nv1 = nv1 < 0 ? 0 : (nv1 > 16 ? 16 : nv1);
    if (!vj) { nv0 = 0; nv1 = 0; }

    // weights: 4 gate rows x 32 k = 8 named h16 vectors (register-resident)
#define LWG(nm, row0) h16 nm##0, nm##1; { \
        const float* wp = Whh + (row0 + u) * LH + kbase; \
        nm##0 = load_w16(wp, nv0); nm##1 = load_w16(wp + 16, nv1); }
    LWG(wi, 0) LWG(wf, 125) LWG(wg, 250) LWG(wo, 375)
#undef LWG

    for (int q = tid; q < 2 * 4 * 48; q += 512) h_lds[q] = (_Float16)0.f;
    float c = 0.f;
    __syncthreads();

    float4 pv4 = *reinterpret_cast<const float4*>(pre + (dir ? (T_SEQ - 1) : 0) * G4 + u * 4);

    for (int s = 0; s < T_SEQ; ++s) {
        const int t  = dir ? (T_SEQ - 1 - s) : s;
        const int sn = (s + 1 < T_SEQ) ? s + 1 : s;
        const int tn = dir ? (T_SEQ - 1 - sn) : sn;
        float4 pvn = *reinterpret_cast<const float4*>(pre + tn * G4 + u * 4);  // prefetch

        const _Float16* hp = &h_lds[(s & 1) * 192 + kp * 48];
        h16 hv0 = *reinterpret_cast<const h16*>(hp);
        h16 hv1 = *reinterpret_cast<const h16*>(hp + 16);

        float ai = mac16(wi1, hv1, mac16(wi0, hv0, 0.f));
        float af = mac16(wf1, hv1, mac16(wf0, hv0, 0.f));
        float ag = mac16(wg1, hv1, mac16(wg0, hv0, 0.f));
        float ao = mac16(wo1, hv1, mac16(wo0, hv0, 0.f));
        ai = red4(ai); af = red4(af); ag = red4(ag); ao = red4(ao);

        float gi = fsig(ai + pv4.x);
        float gf = fsig(af + pv4.y);
        float gg = ftanh(ag + pv4.z);
        float go = fsig(ao + pv4.w);
        c = gf * c + gi * gg;
        float hnew = go * ftanh(c);

        if (vj && kp == (jg >> 5))
            h_lds[((s + 1) & 1) * 192 + kp * 48 + (jg & 31)] = (_Float16)hnew;
        if (vj && kp == 0)
            hout[t * 250 + col0 + jg] = hnew;
        __syncthreads();
        pv4 = pvn;
    }
}

// ---------------- head' = h2 @ FOH + bias ; mod = h2 @ FOM
__global__ void k_headmod(const float* __restrict__ h2,
                          const float* __restrict__ FOH, const float* __restrict__ FOM,
                          const float* __restrict__ bias,
                          float* __restrict__ headp, float* __restrict__ modv) {
    __shared__ float hs[250];
    int t = blockIdx.x, tid = threadIdx.x;   // block 256
    for (int k = tid; k < 250; k += 256) hs[k] = h2[t * 250 + k];
    __syncthreads();
    if (tid < 100) {
        float a = 0.f;
        #pragma unroll 5
        for (int k = 0; k < 250; ++k) a += hs[k] * FOH[k * 100 + tid];
        headp[t * 100 + tid] = a + bias[tid];
    } else if (tid >= 128 && tid < 228) {
        int h = tid - 128;
        float a = 0.f;
        #pragma unroll 5
        for (int k = 0; k < 250; ++k) a += hs[k] * FOM[k * 100 + h];
        modv[t * 100 + h] = a;
    }
}

// ---------------- scores[i][j] = sum_h tanh(head'[i][h] + mod[j][h]) * outW[h]
__global__ void k_score(const float* __restrict__ headp, const float* __restrict__ modv,
                        const float* __restrict__ outw, float* __restrict__ out) {
    __shared__ float hh[16][100];
    __shared__ float mm[16][100];
    __shared__ float ow[100];
    const int bi = blockIdx.y, bj = blockIdx.x;
    const int tx = threadIdx.x, ty = threadIdx.y;   // 16x16
    const int tid = ty * 16 + tx;
    for (int q = tid; q < 1600; q += 256) {
        int r = q / 100, cidx = q % 100;
        hh[r][cidx] = headp[(bi * 16 + r) * 100 + cidx];
        mm[r][cidx] = modv[(bj * 16 + r) * 100 + cidx];
    }
    if (tid < 100) ow[tid] = outw[tid];
    __syncthreads();
    float acc = 0.f;
    #pragma unroll 4
    for (int h = 0; h < 100; ++h) {
        acc += ftanh(hh[ty][h] + mm[tx][h]) * ow[h];
    }
    out[(bi * 16 + ty) * 1024 + (bj * 16 + tx)] = acc;
}

extern "C" void kernel_launch(void* const* d_in, const int* in_sizes, int n_in,
                              void* d_out, int out_size, void* d_ws, size_t ws_size,
                              hipStream_t stream) {
    const int*   wid    = (const int*)d_in[0];
    const int*   pid    = (const int*)d_in[1];
    const float* W_emb  = (const float*)d_in[2];
    const float* P_emb  = (const float*)d_in[3];
    const float* Wih_f0 = (const float*)d_in[4];
    const float* Whh_f0 = (const float*)d_in[5];
    const float* b_f0   = (const float*)d_in[6];
    const float* Wih_b0 = (const float*)d_in[7];
    const float* Whh_b0 = (const float*)d_in[8];
    const float* b_b0   = (const float*)d_in[9];
    const float* Wih_f1 = (const float*)d_in[10];
    const float* Whh_f1 = (const float*)d_in[11];
    const float* b_f1   = (const float*)d_in[12];
    const float* Wih_b1 = (const float*)d_in[13];
    const float* Whh_b1 = (const float*)d_in[14];
    const float* b_b1   = (const float*)d_in[15];
    const float* FOH    = (const float*)d_in[16];
    const float* FOM    = (const float*)d_in[17];
    const float* hidB   = (const float*)d_in[18];
    const float* outW   = (const float*)d_in[19];
    float* out = (float*)d_out;
    float* ws  = (float*)d_ws;

    float* pf    = ws;                  // 1024*500 (interleaved [t][u][gate])
    float* pb    = pf    + 512000;
    float* h1    = pb    + 512000;      // 1024*250
    float* h2    = h1    + 256000;
    float* headp = h2    + 256000;      // 1024*100
    float* modv  = headp + 102400;

    k_preproj0<<<256, 512, 0, stream>>>(wid, pid, W_emb, P_emb,
                                        Wih_f0, b_f0, Wih_b0, b_b0, pf, pb);
    k_scan<<<2, 512, 0, stream>>>(pf, Whh_f0, pb, Whh_b0, h1);

    k_preproj1<<<256, 512, 0, stream>>>(h1, Wih_f1, b_f1, Wih_b1, b_b1, pf, pb);
    k_scan<<<2, 512, 0, stream>>>(pf, Whh_f1, pb, Whh_b1, h2);

    k_headmod<<<T_SEQ, 256, 0, stream>>>(h2, FOH, FOM, hidB, headp, modv);
    dim3 gs(64, 64), bs(16, 16);
    k_score<<<gs, bs, 0, stream>>>(headp, modv, outW, out);
}

// Round 5
// 1287.640 us; speedup vs baseline: 2.8698x; 1.0741x over previous
//
#include <hip/hip_runtime.h>
#include <math.h>

#define T_SEQ 1024
#define LH 125      // lstm hidden
#define G4 500      // 4*L gates

typedef _Float16 h16 __attribute__((ext_vector_type(16)));

__device__ __forceinline__ float ftanh(float x) {
    float e = __builtin_amdgcn_exp2f(x * -2.8853900817779268f);
    return 2.f * __builtin_amdgcn_rcpf(1.f + e) - 1.f;
}

// DPP quad-perm moves: xor1 = [1,0,3,2] = 0xB1, xor2 = [2,3,0,1] = 0x4E
__device__ __forceinline__ float dpp_xor1(float x) {
    int xi = __float_as_int(x);
    return __int_as_float(__builtin_amdgcn_update_dpp(xi, xi, 0xB1, 0xF, 0xF, true));
}
__device__ __forceinline__ float dpp_xor2(float x) {
    int xi = __float_as_int(x);
    return __int_as_float(__builtin_amdgcn_update_dpp(xi, xi, 0x4E, 0xF, 0xF, true));
}

// Load up to 16 f32 weights -> f16 vector, compile-time indices only (stays SSA)
__device__ __forceinline__ h16 load_w16(const float* __restrict__ wp, int nvalid) {
    h16 r;
#define SETW(i) r[i] = ((i) < nvalid) ? (_Float16)wp[i] : (_Float16)0.f;
    SETW(0) SETW(1) SETW(2) SETW(3) SETW(4) SETW(5) SETW(6) SETW(7)
    SETW(8) SETW(9) SETW(10) SETW(11) SETW(12) SETW(13) SETW(14) SETW(15)
#undef SETW
    return r;
}

// 16-term f16 dot via 8x v_dot2_f32_f16, f32 accumulate
__device__ __forceinline__ float mac16(h16 w, h16 h, float acc) {
#define DOT(p) acc = __builtin_amdgcn_fdot2( \
        __builtin_shufflevector(w, w, 2*(p), 2*(p)+1), \
        __builtin_shufflevector(h, h, 2*(p), 2*(p)+1), acc, false);
    DOT(0) DOT(1) DOT(2) DOT(3) DOT(4) DOT(5) DOT(6) DOT(7)
#undef DOT
    return acc;
}

// ---------------- layer-0 input projection, embedding fused, 4 timesteps/block
// Stores pre in interleaved layout: pre[t][unit][gate] (gate: 0=i,1=f,2=g,3=o)
__global__ void k_preproj0(const int* __restrict__ wid, const int* __restrict__ pid,
                           const float* __restrict__ W_emb, const float* __restrict__ P_emb,
                           const float* __restrict__ Wf, const float* __restrict__ bf,
                           const float* __restrict__ Wb, const float* __restrict__ bb,
                           float* __restrict__ pf, float* __restrict__ pb) {
    __shared__ float xs[4][128];
    const int t0 = blockIdx.x * 4;
    const int tid = threadIdx.x;   // 512
    for (int tt = 0; tt < 4; ++tt) {
        int t = t0 + tt;
        for (int k = tid; k < 125; k += 512)
            xs[tt][k] = (k < 100) ? W_emb[wid[t] * 100 + k] : P_emb[pid[t] * 25 + (k - 100)];
    }
    __syncthreads();
    const int j = tid;
    if (j < G4) {
        const float* wf = Wf + j * 125;
        const float* wb = Wb + j * 125;
        float af0 = bf[j], af1 = af0, af2 = af0, af3 = af0;
        float ab0 = bb[j], ab1 = ab0, ab2 = ab0, ab3 = ab0;
        #pragma unroll 5
        for (int k = 0; k < 125; ++k) {
            float wfk = wf[k], wbk = wb[k];
            af0 += wfk * xs[0][k]; af1 += wfk * xs[1][k];
            af2 += wfk * xs[2][k]; af3 += wfk * xs[3][k];
            ab0 += wbk * xs[0][k]; ab1 += wbk * xs[1][k];
            ab2 += wbk * xs[2][k]; ab3 += wbk * xs[3][k];
        }
        int g = j / 125, u = j - g * 125;
        int off = u * 4 + g;
        pf[(t0 + 0) * G4 + off] = af0; pf[(t0 + 1) * G4 + off] = af1;
        pf[(t0 + 2) * G4 + off] = af2; pf[(t0 + 3) * G4 + off] = af3;
        pb[(t0 + 0) * G4 + off] = ab0; pb[(t0 + 1) * G4 + off] = ab1;
        pb[(t0 + 2) * G4 + off] = ab2; pb[(t0 + 3) * G4 + off] = ab3;
    }
}

// ---------------- layer-1 input projection (input = h1, K=250), interleaved store
__global__ void k_preproj1(const float* __restrict__ h1,
                           const float* __restrict__ Wf, const float* __restrict__ bf,
                           const float* __restrict__ Wb, const float* __restrict__ bb,
                           float* __restrict__ pf, float* __restrict__ pb) {
    __shared__ float xs[4][256];
    const int t0 = blockIdx.x * 4;
    const int tid = threadIdx.x;   // 512
    for (int tt = 0; tt < 4; ++tt) {
        int t = t0 + tt;
        for (int k = tid; k < 250; k += 512) xs[tt][k] = h1[t * 250 + k];
    }
    __syncthreads();
    const int j = tid;
    if (j < G4) {
        const float* wf = Wf + j * 250;
        const float* wb = Wb + j * 250;
        float af0 = bf[j], af1 = af0, af2 = af0, af3 = af0;
        float ab0 = bb[j], ab1 = ab0, ab2 = ab0, ab3 = ab0;
        #pragma unroll 5
        for (int k = 0; k < 250; ++k) {
            float wfk = wf[k], wbk = wb[k];
            af0 += wfk * xs[0][k]; af1 += wfk * xs[1][k];
            af2 += wfk * xs[2][k]; af3 += wfk * xs[3][k];
            ab0 += wbk * xs[0][k]; ab1 += wbk * xs[1][k];
            ab2 += wbk * xs[2][k]; ab3 += wbk * xs[3][k];
        }
        int g = j / 125, u = j - g * 125;
        int off = u * 4 + g;
        pf[(t0 + 0) * G4 + off] = af0; pf[(t0 + 1) * G4 + off] = af1;
        pf[(t0 + 2) * G4 + off] = af2; pf[(t0 + 3) * G4 + off] = af3;
        pb[(t0 + 0) * G4 + off] = ab0; pb[(t0 + 1) * G4 + off] = ab1;
        pb[(t0 + 2) * G4 + off] = ab2; pb[(t0 + 3) * G4 + off] = ab3;
    }
}

// ---------------- sequential LSTM scan, one 512-thread block per direction
// jg = tid>>2 owns hidden unit jg; kp = tid&3 owns k-slice [32kp, 32kp+32) AND gate kp.
// Dots: each lane partial-dots all 4 gate rows over its k-slice.
// Butterfly transpose-reduce leaves gate kp's full sum in lane kp; one nonlinearity per
// lane; 3 DPP movs + selects reassemble {f, o, i*g} per lane for the (redundant,
// deterministic) c/h update. One barrier per step. h f16 double-buffered in LDS.
__global__ void __launch_bounds__(512, 1)
k_scan(const float* __restrict__ pf, const float* __restrict__ Wf,
       const float* __restrict__ pb, const float* __restrict__ Wb,
       float* __restrict__ hout) {
    const int dir = blockIdx.x;
    const float* __restrict__ pre = dir ? pb : pf;   // [T][125][4]
    const float* __restrict__ Whh = dir ? Wb : Wf;
    const int col0 = dir ? 0 : 125;

    __shared__ __align__(32) _Float16 h_lds[2 * 4 * 48];  // 2 buf x 4 regions x (32 used + 16 pad)

    const int tid = threadIdx.x;
    const int kp  = tid & 3;
    const int jg  = tid >> 2;      // 0..127
    const int kbase = kp * 32;
    const bool vj = (jg < LH);
    const int u = vj ? jg : (LH - 1);

    const bool b0 = (kp & 1) != 0;
    const bool b1 = (kp & 2) != 0;
    const bool lowpair = (kp < 2);

    // valid k counts for the two 16-wide sub-slices
    int nv0 = LH - kbase;       nv0 = nv0 < 0 ? 0 : (nv0 > 16 ? 16 : nv0);
    int nv1 = LH - kbase - 16;  nv1 = nv1 < 0 ? 0 : (nv1 > 16 ? 16 : nv1);
    if (!vj) { nv0 = 0; nv1 = 0; }

    // weights: 4 gate rows x 32 k = 8 named h16 vectors (register-resident)
#define LWG(nm, row0) h16 nm##0, nm##1; { \
        const float* wp = Whh + (row0 + u) * LH + kbase; \
        nm##0 = load_w16(wp, nv0); nm##1 = load_w16(wp + 16, nv1); }
    LWG(wi, 0) LWG(wf, 125) LWG(wg, 250) LWG(wo, 375)
#undef LWG

    // own-gate nonlinearity constants: sigmoid for kp in {0,1,3}, tanh for kp==2
    const bool is_sig = (kp != 2);
    const float Ac  = is_sig ? 1.f : 2.f;
    const float Bc2 = is_sig ? -1.4426950408889634f : -2.8853900817779268f; // B/ln2
    const float Cc  = is_sig ? 0.f : -1.f;

    for (int q = tid; q < 2 * 4 * 48; q += 512) h_lds[q] = (_Float16)0.f;
    float c = 0.f;
    __syncthreads();

    // per-lane pre pointer: element [t][u][kp]; advances by +-G4 per step
    const float* pp = pre + (dir ? (T_SEQ - 1) * G4 : 0) + u * 4 + kp;
    const int pstride = dir ? -G4 : G4;
    float pv = *pp;

    for (int s = 0; s < T_SEQ; ++s) {
        const int t = dir ? (T_SEQ - 1 - s) : s;
        const float* pn = (s + 1 < T_SEQ) ? pp + pstride : pp;
        float pvn = *pn;                       // prefetch next step's pre

        const _Float16* hp = &h_lds[(s & 1) * 192 + kp * 48];
        h16 hv0 = *reinterpret_cast<const h16*>(hp);
        h16 hv1 = *reinterpret_cast<const h16*>(hp + 16);

        float ai = mac16(wi1, hv1, mac16(wi0, hv0, 0.f));
        float af = mac16(wf1, hv1, mac16(wf0, hv0, 0.f));
        float ag = mac16(wg1, hv1, mac16(wg0, hv0, 0.f));
        float ao = mac16(wo1, hv1, mac16(wo0, hv0, 0.f));

        // butterfly transpose-reduce: lane kp ends with gate kp's full sum
        float uL = lowpair ? ai : ag;
        float vL = lowpair ? ag : ai;
        float A2 = uL + dpp_xor2(vL);
        float wL = lowpair ? af : ao;
        float xL = lowpair ? ao : af;
        float B2 = wL + dpp_xor2(xL);
        float snd = b0 ? A2 : B2;
        float own = b0 ? B2 : A2;
        float gsum = own + dpp_xor1(snd);

        // one nonlinearity per lane (own gate)
        float gv = Ac * __builtin_amdgcn_rcpf(
                       1.f + __builtin_amdgcn_exp2f(Bc2 * (gsum + pv))) + Cc;

        // quad all-gather: r1 = gate kp^1, r2 = gate kp^2, r3 = gate kp^3
        float r1 = dpp_xor1(gv);
        float r2 = dpp_xor2(gv);
        float r3 = dpp_xor2(r1);

        // reassemble per-lane: m = i*g, gfv = f, gov = o
        float m   = (b0 ? r1 : gv) * (b0 ? r3 : r2);
        float s01 = b0 ? gv : r1;
        float s23 = b0 ? r2 : r3;
        float gfv = b1 ? s23 : s01;
        float gov = b1 ? s01 : s23;

        c = gfv * c + m;
        float hnew = gov * ftanh(c);

        if (vj && kp == (jg >> 5))
            h_lds[((s + 1) & 1) * 192 + kp * 48 + (jg & 31)] = (_Float16)hnew;
        if (vj && kp == 0)
            hout[t * 250 + col0 + jg] = hnew;
        __syncthreads();
        pv = pvn;
        pp = pn;
    }
}

// ---------------- head' = h2 @ FOH + bias ; mod = h2 @ FOM
__global__ void k_headmod(const float* __restrict__ h2,
                          const float* __restrict__ FOH, const float* __restrict__ FOM,
                          const float* __restrict__ bias,
                          float* __restrict__ headp, float* __restrict__ modv) {
    __shared__ float hs[250];
    int t = blockIdx.x, tid = threadIdx.x;   // block 256
    for (int k = tid; k < 250; k += 256) hs[k] = h2[t * 250 + k];
    __syncthreads();
    if (tid < 100) {
        float a = 0.f;
        #pragma unroll 5
        for (int k = 0; k < 250; ++k) a += hs[k] * FOH[k * 100 + tid];
        headp[t * 100 + tid] = a + bias[tid];
    } else if (tid >= 128 && tid < 228) {
        int h = tid - 128;
        float a = 0.f;
        #pragma unroll 5
        for (int k = 0; k < 250; ++k) a += hs[k] * FOM[k * 100 + h];
        modv[t * 100 + h] = a;
    }
}

// ---------------- scores[i][j] = sum_h tanh(head'[i][h] + mod[j][h]) * outW[h]
__global__ void k_score(const float* __restrict__ headp, const float* __restrict__ modv,
                        const float* __restrict__ outw, float* __restrict__ out) {
    __shared__ float hh[16][100];
    __shared__ float mm[16][100];
    __shared__ float ow[100];
    const int bi = blockIdx.y, bj = blockIdx.x;
    const int tx = threadIdx.x, ty = threadIdx.y;   // 16x16
    const int tid = ty * 16 + tx;
    for (int q = tid; q < 1600; q += 256) {
        int r = q / 100, cidx = q % 100;
        hh[r][cidx] = headp[(bi * 16 + r) * 100 + cidx];
        mm[r][cidx] = modv[(bj * 16 + r) * 100 + cidx];
    }
    if (tid < 100) ow[tid] = outw[tid];
    __syncthreads();
    float acc = 0.f;
    #pragma unroll 4
    for (int h = 0; h < 100; ++h) {
        float e = __builtin_amdgcn_exp2f((hh[ty][h] + mm[tx][h]) * -2.8853900817779268f);
        acc += (2.f * __builtin_amdgcn_rcpf(1.f + e) - 1.f) * ow[h];
    }
    out[(bi * 16 + ty) * 1024 + (bj * 16 + tx)] = acc;
}

extern "C" void kernel_launch(void* const* d_in, const int* in_sizes, int n_in,
                              void* d_out, int out_size, void* d_ws, size_t ws_size,
                              hipStream_t stream) {
    const int*   wid    = (const int*)d_in[0];
    const int*   pid    = (const int*)d_in[1];
    const float* W_emb  = (const float*)d_in[2];
    const float* P_emb  = (const float*)d_in[3];
    const float* Wih_f0 = (const float*)d_in[4];
    const float* Whh_f0 = (const float*)d_in[5];
    const float* b_f0   = (const float*)d_in[6];
    const float* Wih_b0 = (const float*)d_in[7];
    const float* Whh_b0 = (const float*)d_in[8];
    const float* b_b0   = (const float*)d_in[9];
    const float* Wih_f1 = (const float*)d_in[10];
    const float* Whh_f1 = (const float*)d_in[11];
    const float* b_f1   = (const float*)d_in[12];
    const float* Wih_b1 = (const float*)d_in[13];
    const float* Whh_b1 = (const float*)d_in[14];
    const float* b_b1   = (const float*)d_in[15];
    const float* FOH    = (const float*)d_in[16];
    const float* FOM    = (const float*)d_in[17];
    const float* hidB   = (const float*)d_in[18];
    const float* outW   = (const float*)d_in[19];
    float* out = (float*)d_out;
    float* ws  = (float*)d_ws;

    float* pf    = ws;                  // 1024*500 (interleaved [t][u][gate])
    float* pb    = pf    + 512000;
    float* h1    = pb    + 512000;      // 1024*250
    float* h2    = h1    + 256000;
    float* headp = h2    + 256000;      // 1024*100
    float* modv  = headp + 102400;

    k_preproj0<<<256, 512, 0, stream>>>(wid, pid, W_emb, P_emb,
                                        Wih_f0, b_f0, Wih_b0, b_b0, pf, pb);
    k_scan<<<2, 512, 0, stream>>>(pf, Whh_f0, pb, Whh_b0, h1);

    k_preproj1<<<256, 512, 0, stream>>>(h1, Wih_f1, b_f1, Wih_b1, b_b1, pf, pb);
    k_scan<<<2, 512, 0, stream>>>(pf, Whh_f1, pb, Whh_b1, h2);

    k_headmod<<<T_SEQ, 256, 0, stream>>>(h2, FOH, FOM, hidB, headp, modv);
    dim3 gs(64, 64), bs(16, 16);
    k_score<<<gs, bs, 0, stream>>>(headp, modv, outW, out);
}

// Round 6
// 1287.513 us; speedup vs baseline: 2.8701x; 1.0001x over previous
//
#include <hip/hip_runtime.h>
#include <math.h>

#define T_SEQ 1024
#define LH 125      // lstm hidden
#define G4 500      // 4*L gates

typedef _Float16 h16 __attribute__((ext_vector_type(16)));

__device__ __forceinline__ float ftanh(float x) {
    float e = __builtin_amdgcn_exp2f(x * -2.8853900817779268f);
    return 2.f * __builtin_amdgcn_rcpf(1.f + e) - 1.f;
}

// DPP quad-perm moves: xor1 = [1,0,3,2] = 0xB1, xor2 = [2,3,0,1] = 0x4E
__device__ __forceinline__ float dpp_xor1(float x) {
    int xi = __float_as_int(x);
    return __int_as_float(__builtin_amdgcn_update_dpp(xi, xi, 0xB1, 0xF, 0xF, true));
}
__device__ __forceinline__ float dpp_xor2(float x) {
    int xi = __float_as_int(x);
    return __int_as_float(__builtin_amdgcn_update_dpp(xi, xi, 0x4E, 0xF, 0xF, true));
}

// Load up to 16 f32 weights -> f16 vector, compile-time indices only (stays SSA)
__device__ __forceinline__ h16 load_w16(const float* __restrict__ wp, int nvalid) {
    h16 r;
#define SETW(i) r[i] = ((i) < nvalid) ? (_Float16)wp[i] : (_Float16)0.f;
    SETW(0) SETW(1) SETW(2) SETW(3) SETW(4) SETW(5) SETW(6) SETW(7)
    SETW(8) SETW(9) SETW(10) SETW(11) SETW(12) SETW(13) SETW(14) SETW(15)
#undef SETW
    return r;
}

// 16-term f16 dot via 8x v_dot2_f32_f16, f32 accumulate
__device__ __forceinline__ float mac16(h16 w, h16 h, float acc) {
#define DOT(p) acc = __builtin_amdgcn_fdot2( \
        __builtin_shufflevector(w, w, 2*(p), 2*(p)+1), \
        __builtin_shufflevector(h, h, 2*(p), 2*(p)+1), acc, false);
    DOT(0) DOT(1) DOT(2) DOT(3) DOT(4) DOT(5) DOT(6) DOT(7)
#undef DOT
    return acc;
}

// ---------------- layer-0 input projection, embedding fused, 4 timesteps/block
// Stores pre in interleaved layout: pre[t][unit][gate] (gate: 0=i,1=f,2=g,3=o)
__global__ void k_preproj0(const int* __restrict__ wid, const int* __restrict__ pid,
                           const float* __restrict__ W_emb, const float* __restrict__ P_emb,
                           const float* __restrict__ Wf, const float* __restrict__ bf,
                           const float* __restrict__ Wb, const float* __restrict__ bb,
                           float* __restrict__ pf, float* __restrict__ pb) {
    __shared__ float xs[4][128];
    const int t0 = blockIdx.x * 4;
    const int tid = threadIdx.x;   // 512
    for (int tt = 0; tt < 4; ++tt) {
        int t = t0 + tt;
        for (int k = tid; k < 125; k += 512)
            xs[tt][k] = (k < 100) ? W_emb[wid[t] * 100 + k] : P_emb[pid[t] * 25 + (k - 100)];
    }
    __syncthreads();
    const int j = tid;
    if (j < G4) {
        const float* wf = Wf + j * 125;
        const float* wb = Wb + j * 125;
        float af0 = bf[j], af1 = af0, af2 = af0, af3 = af0;
        float ab0 = bb[j], ab1 = ab0, ab2 = ab0, ab3 = ab0;
        #pragma unroll 5
        for (int k = 0; k < 125; ++k) {
            float wfk = wf[k], wbk = wb[k];
            af0 += wfk * xs[0][k]; af1 += wfk * xs[1][k];
            af2 += wfk * xs[2][k]; af3 += wfk * xs[3][k];
            ab0 += wbk * xs[0][k]; ab1 += wbk * xs[1][k];
            ab2 += wbk * xs[2][k]; ab3 += wbk * xs[3][k];
        }
        int g = j / 125, u = j - g * 125;
        int off = u * 4 + g;
        pf[(t0 + 0) * G4 + off] = af0; pf[(t0 + 1) * G4 + off] = af1;
        pf[(t0 + 2) * G4 + off] = af2; pf[(t0 + 3) * G4 + off] = af3;
        pb[(t0 + 0) * G4 + off] = ab0; pb[(t0 + 1) * G4 + off] = ab1;
        pb[(t0 + 2) * G4 + off] = ab2; pb[(t0 + 3) * G4 + off] = ab3;
    }
}

// ---------------- layer-1 input projection (input = h1, K=250), interleaved store
__global__ void k_preproj1(const float* __restrict__ h1,
                           const float* __restrict__ Wf, const float* __restrict__ bf,
                           const float* __restrict__ Wb, const float* __restrict__ bb,
                           float* __restrict__ pf, float* __restrict__ pb) {
    __shared__ float xs[4][256];
    const int t0 = blockIdx.x * 4;
    const int tid = threadIdx.x;   // 512
    for (int tt = 0; tt < 4; ++tt) {
        int t = t0 + tt;
        for (int k = tid; k < 250; k += 512) xs[tt][k] = h1[t * 250 + k];
    }
    __syncthreads();
    const int j = tid;
    if (j < G4) {
        const float* wf = Wf + j * 250;
        const float* wb = Wb + j * 250;
        float af0 = bf[j], af1 = af0, af2 = af0, af3 = af0;
        float ab0 = bb[j], ab1 = ab0, ab2 = ab0, ab3 = ab0;
        #pragma unroll 5
        for (int k = 0; k < 250; ++k) {
            float wfk = wf[k], wbk = wb[k];
            af0 += wfk * xs[0][k]; af1 += wfk * xs[1][k];
            af2 += wfk * xs[2][k]; af3 += wfk * xs[3][k];
            ab0 += wbk * xs[0][k]; ab1 += wbk * xs[1][k];
            ab2 += wbk * xs[2][k]; ab3 += wbk * xs[3][k];
        }
        int g = j / 125, u = j - g * 125;
        int off = u * 4 + g;
        pf[(t0 + 0) * G4 + off] = af0; pf[(t0 + 1) * G4 + off] = af1;
        pf[(t0 + 2) * G4 + off] = af2; pf[(t0 + 3) * G4 + off] = af3;
        pb[(t0 + 0) * G4 + off] = ab0; pb[(t0 + 1) * G4 + off] = ab1;
        pb[(t0 + 2) * G4 + off] = ab2; pb[(t0 + 3) * G4 + off] = ab3;
    }
}

// ---------------- sequential LSTM scan, one 512-thread block per direction
// jg = tid>>2 owns hidden unit jg; kp = tid&3 owns k-slice [32kp, 32kp+32) AND gate kp.
// amdgpu_waves_per_eu(2,2): pin occupancy to the pigeonhole minimum so the register
// allocator uses the full 256-reg arch-VGPR budget instead of homing the weight
// vectors in AGPRs (v_dot2 can't read AGPRs -> v_accvgpr_read tax per dot).
__global__ void __attribute__((amdgpu_flat_work_group_size(512, 512)))
__attribute__((amdgpu_waves_per_eu(2, 2)))
k_scan(const float* __restrict__ pf, const float* __restrict__ Wf,
       const float* __restrict__ pb, const float* __restrict__ Wb,
       float* __restrict__ hout) {
    const int dir = blockIdx.x;
    const float* __restrict__ pre = dir ? pb : pf;   // [T][125][4]
    const float* __restrict__ Whh = dir ? Wb : Wf;
    const int col0 = dir ? 0 : 125;

    __shared__ __align__(32) _Float16 h_lds[2 * 4 * 48];  // 2 buf x 4 regions x (32 used + 16 pad)

    const int tid = threadIdx.x;
    const int kp  = tid & 3;
    const int jg  = tid >> 2;      // 0..127
    const int kbase = kp * 32;
    const bool vj = (jg < LH);
    const int u = vj ? jg : (LH - 1);

    const bool b0 = (kp & 1) != 0;
    const bool b1 = (kp & 2) != 0;
    const bool lowpair = (kp < 2);

    // valid k counts for the two 16-wide sub-slices
    int nv0 = LH - kbase;       nv0 = nv0 < 0 ? 0 : (nv0 > 16 ? 16 : nv0);
    int nv1 = LH - kbase - 16;  nv1 = nv1 < 0 ? 0 : (nv1 > 16 ? 16 : nv1);
    if (!vj) { nv0 = 0; nv1 = 0; }

    // weights: 4 gate rows x 32 k = 8 named h16 vectors (register-resident)
#define LWG(nm, row0) h16 nm##0, nm##1; { \
        const float* wp = Whh + (row0 + u) * LH + kbase; \
        nm##0 = load_w16(wp, nv0); nm##1 = load_w16(wp + 16, nv1); }
    LWG(wi, 0) LWG(wf, 125) LWG(wg, 250) LWG(wo, 375)
#undef LWG

    // own-gate nonlinearity constants: sigmoid for kp in {0,1,3}, tanh for kp==2
    const bool is_sig = (kp != 2);
    const float Ac  = is_sig ? 1.f : 2.f;
    const float Bc2 = is_sig ? -1.4426950408889634f : -2.8853900817779268f; // B/ln2
    const float Cc  = is_sig ? 0.f : -1.f;

    for (int q = tid; q < 2 * 4 * 48; q += 512) h_lds[q] = (_Float16)0.f;
    float c = 0.f;
    __syncthreads();

    // per-lane pre pointer: element [t][u][kp]; advances by +-G4 per step
    const float* pp = pre + (dir ? (T_SEQ - 1) * G4 : 0) + u * 4 + kp;
    const int pstride = dir ? -G4 : G4;
    float pv = *pp;

    const bool writes_h = vj && (kp == (jg >> 5));
    const bool writes_g = vj && (kp == 0);

    for (int s = 0; s < T_SEQ; ++s) {
        const int t = dir ? (T_SEQ - 1 - s) : s;
        const float* pn = (s + 1 < T_SEQ) ? pp + pstride : pp;
        float pvn = *pn;                       // prefetch next step's pre

        const _Float16* hp = &h_lds[(s & 1) * 192 + kp * 48];
        h16 hv0 = *reinterpret_cast<const h16*>(hp);
        h16 hv1 = *reinterpret_cast<const h16*>(hp + 16);

        float ai = mac16(wi1, hv1, mac16(wi0, hv0, 0.f));
        float af = mac16(wf1, hv1, mac16(wf0, hv0, 0.f));
        float ag = mac16(wg1, hv1, mac16(wg0, hv0, 0.f));
        float ao = mac16(wo1, hv1, mac16(wo0, hv0, 0.f));

        // butterfly transpose-reduce: lane kp ends with gate kp's full sum
        float uL = lowpair ? ai : ag;
        float vL = lowpair ? ag : ai;
        float A2 = uL + dpp_xor2(vL);
        float wL = lowpair ? af : ao;
        float xL = lowpair ? ao : af;
        float B2 = wL + dpp_xor2(xL);
        float snd = b0 ? A2 : B2;
        float own = b0 ? B2 : A2;
        float gsum = own + dpp_xor1(snd);

        // one nonlinearity per lane (own gate)
        float gv = Ac * __builtin_amdgcn_rcpf(
                       1.f + __builtin_amdgcn_exp2f(Bc2 * (gsum + pv))) + Cc;

        // quad all-gather: r1 = gate kp^1, r2 = gate kp^2, r3 = gate kp^3
        float r1 = dpp_xor1(gv);
        float r2 = dpp_xor2(gv);
        float r3 = dpp_xor2(r1);

        // reassemble per-lane: m = i*g, gfv = f, gov = o
        float m   = (b0 ? r1 : gv) * (b0 ? r3 : r2);
        float s01 = b0 ? gv : r1;
        float s23 = b0 ? r2 : r3;
        float gfv = b1 ? s23 : s01;
        float gov = b1 ? s01 : s23;

        c = gfv * c + m;
        float hnew = gov * ftanh(c);

        if (writes_h)
            h_lds[((s + 1) & 1) * 192 + kp * 48 + (jg & 31)] = (_Float16)hnew;
        if (writes_g)
            hout[t * 250 + col0 + jg] = hnew;
        __syncthreads();
        pv = pvn;
        pp = pn;
    }
}

// ---------------- head' = h2 @ FOH + bias ; mod = h2 @ FOM
__global__ void k_headmod(const float* __restrict__ h2,
                          const float* __restrict__ FOH, const float* __restrict__ FOM,
                          const float* __restrict__ bias,
                          float* __restrict__ headp, float* __restrict__ modv) {
    __shared__ float hs[250];
    int t = blockIdx.x, tid = threadIdx.x;   // block 256
    for (int k = tid; k < 250; k += 256) hs[k] = h2[t * 250 + k];
    __syncthreads();
    if (tid < 100) {
        float a = 0.f;
        #pragma unroll 5
        for (int k = 0; k < 250; ++k) a += hs[k] * FOH[k * 100 + tid];
        headp[t * 100 + tid] = a + bias[tid];
    } else if (tid >= 128 && tid < 228) {
        int h = tid - 128;
        float a = 0.f;
        #pragma unroll 5
        for (int k = 0; k < 250; ++k) a += hs[k] * FOM[k * 100 + h];
        modv[t * 100 + h] = a;
    }
}

// ---------------- scores[i][j] = sum_h tanh(head'[i][h] + mod[j][h]) * outW[h]
__global__ void k_score(const float* __restrict__ headp, const float* __restrict__ modv,
                        const float* __restrict__ outw, float* __restrict__ out) {
    __shared__ float hh[16][100];
    __shared__ float mm[16][100];
    __shared__ float ow[100];
    const int bi = blockIdx.y, bj = blockIdx.x;
    const int tx = threadIdx.x, ty = threadIdx.y;   // 16x16
    const int tid = ty * 16 + tx;
    for (int q = tid; q < 1600; q += 256) {
        int r = q / 100, cidx = q % 100;
        hh[r][cidx] = headp[(bi * 16 + r) * 100 + cidx];
        mm[r][cidx] = modv[(bj * 16 + r) * 100 + cidx];
    }
    if (tid < 100) ow[tid] = outw[tid];
    __syncthreads();
    float acc = 0.f;
    #pragma unroll 4
    for (int h = 0; h < 100; ++h) {
        float e = __builtin_amdgcn_exp2f((hh[ty][h] + mm[tx][h]) * -2.8853900817779268f);
        acc += (2.f * __builtin_amdgcn_rcpf(1.f + e) - 1.f) * ow[h];
    }
    out[(bi * 16 + ty) * 1024 + (bj * 16 + tx)] = acc;
}

extern "C" void kernel_launch(void* const* d_in, const int* in_sizes, int n_in,
                              void* d_out, int out_size, void* d_ws, size_t ws_size,
                              hipStream_t stream) {
    const int*   wid    = (const int*)d_in[0];
    const int*   pid    = (const int*)d_in[1];
    const float* W_emb  = (const float*)d_in[2];
    const float* P_emb  = (const float*)d_in[3];
    const float* Wih_f0 = (const float*)d_in[4];
    const float* Whh_f0 = (const float*)d_in[5];
    const float* b_f0   = (const float*)d_in[6];
    const float* Wih_b0 = (const float*)d_in[7];
    const float* Whh_b0 = (const float*)d_in[8];
    const float* b_b0   = (const float*)d_in[9];
    const float* Wih_f1 = (const float*)d_in[10];
    const float* Whh_f1 = (const float*)d_in[11];
    const float* b_f1   = (const float*)d_in[12];
    const float* Wih_b1 = (const float*)d_in[13];
    const float* Whh_b1 = (const float*)d_in[14];
    const float* b_b1   = (const float*)d_in[15];
    const float* FOH    = (const float*)d_in[16];
    const float* FOM    = (const float*)d_in[17];
    const float* hidB   = (const float*)d_in[18];
    const float* outW   = (const float*)d_in[19];
    float* out = (float*)d_out;
    float* ws  = (float*)d_ws;

    float* pf    = ws;                  // 1024*500 (interleaved [t][u][gate])
    float* pb    = pf    + 512000;
    float* h1    = pb    + 512000;      // 1024*250
    float* h2    = h1    + 256000;
    float* headp = h2    + 256000;      // 1024*100
    float* modv  = headp + 102400;

    k_preproj0<<<256, 512, 0, stream>>>(wid, pid, W_emb, P_emb,
                                        Wih_f0, b_f0, Wih_b0, b_b0, pf, pb);
    k_scan<<<2, 512, 0, stream>>>(pf, Whh_f0, pb, Whh_b0, h1);

    k_preproj1<<<256, 512, 0, stream>>>(h1, Wih_f1, b_f1, Wih_b1, b_b1, pf, pb);
    k_scan<<<2, 512, 0, stream>>>(pf, Whh_f1, pb, Whh_b1, h2);

    k_headmod<<<T_SEQ, 256, 0, stream>>>(h2, FOH, FOM, hidB, headp, modv);
    dim3 gs(64, 64), bs(16, 16);
    k_score<<<gs, bs, 0, stream>>>(headp, modv, outW, out);
}

// Round 7
// 1200.357 us; speedup vs baseline: 3.0785x; 1.0726x over previous
//
#include <hip/hip_runtime.h>
#include <math.h>

#define T_SEQ 1024
#define LH 125      // lstm hidden
#define G4 500      // 4*L gates

typedef unsigned int v8u __attribute__((ext_vector_type(8)));
typedef _Float16 f16x2 __attribute__((ext_vector_type(2)));

__device__ __forceinline__ float ftanh(float x) {
    float e = __builtin_amdgcn_exp2f(x * -2.8853900817779268f);
    return 2.f * __builtin_amdgcn_rcpf(1.f + e) - 1.f;
}

// DPP quad-perm moves: xor1 = [1,0,3,2] = 0xB1, xor2 = [2,3,0,1] = 0x4E
__device__ __forceinline__ float dpp_xor1(float x) {
    int xi = __float_as_int(x);
    return __int_as_float(__builtin_amdgcn_update_dpp(xi, xi, 0xB1, 0xF, 0xF, true));
}
__device__ __forceinline__ float dpp_xor2(float x) {
    int xi = __float_as_int(x);
    return __int_as_float(__builtin_amdgcn_update_dpp(xi, xi, 0x4E, 0xF, 0xF, true));
}

__device__ __forceinline__ f16x2 as_h2(unsigned int u) {
    return __builtin_bit_cast(f16x2, u);
}

// 16-term f16 dot: 8x v_dot2_f32_f16, operands are compile-time dword extracts
__device__ __forceinline__ float dot8(v8u w, v8u h, float acc) {
#define D8(p) acc = __builtin_amdgcn_fdot2(as_h2(w[p]), as_h2(h[p]), acc, false);
    D8(0) D8(1) D8(2) D8(3) D8(4) D8(5) D8(6) D8(7)
#undef D8
    return acc;
}

// pack 16 f32 weights (with validity mask) into 8 dwords of f16 pairs
__device__ __forceinline__ v8u packw8(const float* __restrict__ wp, int nvalid) {
    v8u r;
#define PW(d) { \
    float a = (2*(d)   < nvalid) ? wp[2*(d)]   : 0.f; \
    float b = (2*(d)+1 < nvalid) ? wp[2*(d)+1] : 0.f; \
    f16x2 t; t[0] = (_Float16)a; t[1] = (_Float16)b; \
    r[d] = __builtin_bit_cast(unsigned int, t); }
    PW(0) PW(1) PW(2) PW(3) PW(4) PW(5) PW(6) PW(7)
#undef PW
    return r;
}

// ---------------- layer-0 input projection, embedding fused, 4 timesteps/block
// Stores pre in interleaved layout: pre[t][unit][gate] (gate: 0=i,1=f,2=g,3=o)
__global__ void k_preproj0(const int* __restrict__ wid, const int* __restrict__ pid,
                           const float* __restrict__ W_emb, const float* __restrict__ P_emb,
                           const float* __restrict__ Wf, const float* __restrict__ bf,
                           const float* __restrict__ Wb, const float* __restrict__ bb,
                           float* __restrict__ pf, float* __restrict__ pb) {
    __shared__ float xs[4][128];
    const int t0 = blockIdx.x * 4;
    const int tid = threadIdx.x;   // 512
    for (int tt = 0; tt < 4; ++tt) {
        int t = t0 + tt;
        for (int k = tid; k < 125; k += 512)
            xs[tt][k] = (k < 100) ? W_emb[wid[t] * 100 + k] : P_emb[pid[t] * 25 + (k - 100)];
    }
    __syncthreads();
    const int j = tid;
    if (j < G4) {
        const float* wf = Wf + j * 125;
        const float* wb = Wb + j * 125;
        float af0 = bf[j], af1 = af0, af2 = af0, af3 = af0;
        float ab0 = bb[j], ab1 = ab0, ab2 = ab0, ab3 = ab0;
        #pragma unroll 5
        for (int k = 0; k < 125; ++k) {
            float wfk = wf[k], wbk = wb[k];
            af0 += wfk * xs[0][k]; af1 += wfk * xs[1][k];
            af2 += wfk * xs[2][k]; af3 += wfk * xs[3][k];
            ab0 += wbk * xs[0][k]; ab1 += wbk * xs[1][k];
            ab2 += wbk * xs[2][k]; ab3 += wbk * xs[3][k];
        }
        int g = j / 125, u = j - g * 125;
        int off = u * 4 + g;
        pf[(t0 + 0) * G4 + off] = af0; pf[(t0 + 1) * G4 + off] = af1;
        pf[(t0 + 2) * G4 + off] = af2; pf[(t0 + 3) * G4 + off] = af3;
        pb[(t0 + 0) * G4 + off] = ab0; pb[(t0 + 1) * G4 + off] = ab1;
        pb[(t0 + 2) * G4 + off] = ab2; pb[(t0 + 3) * G4 + off] = ab3;
    }
}

// ---------------- layer-1 input projection (input = h1, K=250), interleaved store
__global__ void k_preproj1(const float* __restrict__ h1,
                           const float* __restrict__ Wf, const float* __restrict__ bf,
                           const float* __restrict__ Wb, const float* __restrict__ bb,
                           float* __restrict__ pf, float* __restrict__ pb) {
    __shared__ float xs[4][256];
    const int t0 = blockIdx.x * 4;
    const int tid = threadIdx.x;   // 512
    for (int tt = 0; tt < 4; ++tt) {
        int t = t0 + tt;
        for (int k = tid; k < 250; k += 512) xs[tt][k] = h1[t * 250 + k];
    }
    __syncthreads();
    const int j = tid;
    if (j < G4) {
        const float* wf = Wf + j * 250;
        const float* wb = Wb + j * 250;
        float af0 = bf[j], af1 = af0, af2 = af0, af3 = af0;
        float ab0 = bb[j], ab1 = ab0, ab2 = ab0, ab3 = ab0;
        #pragma unroll 5
        for (int k = 0; k < 250; ++k) {
            float wfk = wf[k], wbk = wb[k];
            af0 += wfk * xs[0][k]; af1 += wfk * xs[1][k];
            af2 += wfk * xs[2][k]; af3 += wfk * xs[3][k];
            ab0 += wbk * xs[0][k]; ab1 += wbk * xs[1][k];
            ab2 += wbk * xs[2][k]; ab3 += wbk * xs[3][k];
        }
        int g = j / 125, u = j - g * 125;
        int off = u * 4 + g;
        pf[(t0 + 0) * G4 + off] = af0; pf[(t0 + 1) * G4 + off] = af1;
        pf[(t0 + 2) * G4 + off] = af2; pf[(t0 + 3) * G4 + off] = af3;
        pb[(t0 + 0) * G4 + off] = ab0; pb[(t0 + 1) * G4 + off] = ab1;
        pb[(t0 + 2) * G4 + off] = ab2; pb[(t0 + 3) * G4 + off] = ab3;
    }
}

// ---------------- sequential LSTM scan, one 512-thread block per direction
// jg = tid>>2 owns hidden unit jg; kp = tid&3 owns k-slice [32kp, 32kp+32) AND gate kp.
// All dot operands are uint dwords bit_cast to half2 (forces clean v_dot2 codegen,
// no perm/pack). Global accesses via int offsets. Unroll x2 for compile-time dbuf.
__global__ void __attribute__((amdgpu_flat_work_group_size(512, 512)))
__attribute__((amdgpu_waves_per_eu(2, 2)))
k_scan(const float* __restrict__ pf, const float* __restrict__ Wf,
       const float* __restrict__ pb, const float* __restrict__ Wb,
       float* __restrict__ hout) {
    const int dir = blockIdx.x;
    const float* __restrict__ pre = dir ? pb : pf;   // [T][125][4]
    const float* __restrict__ Whh = dir ? Wb : Wf;
    const int col0 = dir ? 0 : 125;

    __shared__ __align__(32) _Float16 h_lds[2 * 4 * 48];  // 2 buf x 4 regions x (32 used + 16 pad)

    const int tid = threadIdx.x;
    const int kp  = tid & 3;
    const int jg  = tid >> 2;      // 0..127
    const int kbase = kp * 32;
    const bool vj = (jg < LH);
    const int u = vj ? jg : (LH - 1);

    const bool b0 = (kp & 1) != 0;
    const bool b1 = (kp & 2) != 0;
    const bool lowpair = (kp < 2);

    // valid k counts for the two 16-wide sub-slices
    int nv0 = LH - kbase;       nv0 = nv0 < 0 ? 0 : (nv0 > 16 ? 16 : nv0);
    int nv1 = LH - kbase - 16;  nv1 = nv1 < 0 ? 0 : (nv1 > 16 ? 16 : nv1);
    if (!vj) { nv0 = 0; nv1 = 0; }

    // weights: 4 gate rows x 32 k, f16 pairs in uint dwords (register-resident)
#define LWG(lo, hi, row0) v8u lo, hi; { \
        const float* wp = Whh + (row0 + u) * LH + kbase; \
        lo = packw8(wp, nv0); hi = packw8(wp + 16, nv1); }
    LWG(wi_lo, wi_hi, 0) LWG(wf_lo, wf_hi, 125) LWG(wg_lo, wg_hi, 250) LWG(wo_lo, wo_hi, 375)
#undef LWG

    // own-gate nonlinearity constants: sigmoid for kp in {0,1,3}, tanh for kp==2
    const bool is_sig = (kp != 2);
    const float Ac  = is_sig ? 1.f : 2.f;
    const float Bc2 = is_sig ? -1.4426950408889634f : -2.8853900817779268f; // B/ln2
    const float Cc  = is_sig ? 0.f : -1.f;

    for (int q = tid; q < 2 * 4 * 48; q += 512) h_lds[q] = (_Float16)0.f;
    float c = 0.f;
    __syncthreads();

    const bool writes_h = vj && (kp == (jg >> 5));
    const bool writes_g = vj && (kp == 0);

    // int-offset walking pointers (no 64-bit per-lane ptr chains, no clamp:
    // the final one-row-over prefetch provably stays inside the workspace)
    const int pstride = dir ? -G4 : G4;
    int poff = (dir ? (T_SEQ - 1) * G4 : 0) + u * 4 + kp;
    const int gstride = dir ? -250 : 250;
    int goff = (dir ? (T_SEQ - 1) * 250 : 0) + col0 + jg;
    float pv = pre[poff];
    poff += pstride;

    const _Float16* hbase = &h_lds[kp * 48];
    _Float16* hwr = &h_lds[kp * 48 + (jg & 31)];

#define SCAN_STEP(CUR, NXT) { \
    float pvn = pre[poff]; poff += pstride; \
    const _Float16* hp = hbase + (CUR) * 192; \
    v8u hlo = *reinterpret_cast<const v8u*>(hp); \
    v8u hhi = *reinterpret_cast<const v8u*>(hp + 16); \
    float ai = dot8(wi_hi, hhi, dot8(wi_lo, hlo, 0.f)); \
    float af = dot8(wf_hi, hhi, dot8(wf_lo, hlo, 0.f)); \
    float ag = dot8(wg_hi, hhi, dot8(wg_lo, hlo, 0.f)); \
    float ao = dot8(wo_hi, hhi, dot8(wo_lo, hlo, 0.f)); \
    float uL = lowpair ? ai : ag; \
    float vL = lowpair ? ag : ai; \
    float A2 = uL + dpp_xor2(vL); \
    float wL = lowpair ? af : ao; \
    float xL = lowpair ? ao : af; \
    float B2 = wL + dpp_xor2(xL); \
    float snd = b0 ? A2 : B2; \
    float own = b0 ? B2 : A2; \
    float gsum = own + dpp_xor1(snd); \
    float gv = Ac * __builtin_amdgcn_rcpf( \
                   1.f + __builtin_amdgcn_exp2f(Bc2 * (gsum + pv))) + Cc; \
    float r1 = dpp_xor1(gv); \
    float r2 = dpp_xor2(gv); \
    float r3 = dpp_xor2(r1); \
    float m   = (b0 ? r1 : gv) * (b0 ? r3 : r2); \
    float s01 = b0 ? gv : r1; \
    float s23 = b0 ? r2 : r3; \
    float gfv = b1 ? s23 : s01; \
    float gov = b1 ? s01 : s23; \
    c = gfv * c + m; \
    float hnew = gov * ftanh(c); \
    if (writes_h) hwr[(NXT) * 192] = (_Float16)hnew; \
    if (writes_g) hout[goff] = hnew; \
    goff += gstride; \
    __syncthreads(); \
    pv = pvn; \
}

    for (int s2 = 0; s2 < T_SEQ; s2 += 2) {
        SCAN_STEP(0, 1)
        SCAN_STEP(1, 0)
    }
#undef SCAN_STEP
}

// ---------------- head' = h2 @ FOH + bias ; mod = h2 @ FOM
__global__ void k_headmod(const float* __restrict__ h2,
                          const float* __restrict__ FOH, const float* __restrict__ FOM,
                          const float* __restrict__ bias,
                          float* __restrict__ headp, float* __restrict__ modv) {
    __shared__ float hs[250];
    int t = blockIdx.x, tid = threadIdx.x;   // block 256
    for (int k = tid; k < 250; k += 256) hs[k] = h2[t * 250 + k];
    __syncthreads();
    if (tid < 100) {
        float a = 0.f;
        #pragma unroll 5
        for (int k = 0; k < 250; ++k) a += hs[k] * FOH[k * 100 + tid];
        headp[t * 100 + tid] = a + bias[tid];
    } else if (tid >= 128 && tid < 228) {
        int h = tid - 128;
        float a = 0.f;
        #pragma unroll 5
        for (int k = 0; k < 250; ++k) a += hs[k] * FOM[k * 100 + h];
        modv[t * 100 + h] = a;
    }
}

// ---------------- scores[i][j] = sum_h tanh(head'[i][h] + mod[j][h]) * outW[h]
__global__ void k_score(const float* __restrict__ headp, const float* __restrict__ modv,
                        const float* __restrict__ outw, float* __restrict__ out) {
    __shared__ float hh[16][100];
    __shared__ float mm[16][100];
    __shared__ float ow[100];
    const int bi = blockIdx.y, bj = blockIdx.x;
    const int tx = threadIdx.x, ty = threadIdx.y;   // 16x16
    const int tid = ty * 16 + tx;
    for (int q = tid; q < 1600; q += 256) {
        int r = q / 100, cidx = q % 100;
        hh[r][cidx] = headp[(bi * 16 + r) * 100 + cidx];
        mm[r][cidx] = modv[(bj * 16 + r) * 100 + cidx];
    }
    if (tid < 100) ow[tid] = outw[tid];
    __syncthreads();
    float acc = 0.f;
    #pragma unroll 4
    for (int h = 0; h < 100; ++h) {
        float e = __builtin_amdgcn_exp2f((hh[ty][h] + mm[tx][h]) * -2.8853900817779268f);
        acc += (2.f * __builtin_amdgcn_rcpf(1.f + e) - 1.f) * ow[h];
    }
    out[(bi * 16 + ty) * 1024 + (bj * 16 + tx)] = acc;
}

extern "C" void kernel_launch(void* const* d_in, const int* in_sizes, int n_in,
                              void* d_out, int out_size, void* d_ws, size_t ws_size,
                              hipStream_t stream) {
    const int*   wid    = (const int*)d_in[0];
    const int*   pid    = (const int*)d_in[1];
    const float* W_emb  = (const float*)d_in[2];
    const float* P_emb  = (const float*)d_in[3];
    const float* Wih_f0 = (const float*)d_in[4];
    const float* Whh_f0 = (const float*)d_in[5];
    const float* b_f0   = (const float*)d_in[6];
    const float* Wih_b0 = (const float*)d_in[7];
    const float* Whh_b0 = (const float*)d_in[8];
    const float* b_b0   = (const float*)d_in[9];
    const float* Wih_f1 = (const float*)d_in[10];
    const float* Whh_f1 = (const float*)d_in[11];
    const float* b_f1   = (const float*)d_in[12];
    const float* Wih_b1 = (const float*)d_in[13];
    const float* Whh_b1 = (const float*)d_in[14];
    const float* b_b1   = (const float*)d_in[15];
    const float* FOH    = (const float*)d_in[16];
    const float* FOM    = (const float*)d_in[17];
    const float* hidB   = (const float*)d_in[18];
    const float* outW   = (const float*)d_in[19];
    float* out = (float*)d_out;
    float* ws  = (float*)d_ws;

    float* pf    = ws;                  // 1024*500 (interleaved [t][u][gate])
    float* pb    = pf    + 512000;
    float* h1    = pb    + 512000;      // 1024*250
    float* h2    = h1    + 256000;
    float* headp = h2    + 256000;      // 1024*100
    float* modv  = headp + 102400;

    k_preproj0<<<256, 512, 0, stream>>>(wid, pid, W_emb, P_emb,
                                        Wih_f0, b_f0, Wih_b0, b_b0, pf, pb);
    k_scan<<<2, 512, 0, stream>>>(pf, Whh_f0, pb, Whh_b0, h1);

    k_preproj1<<<256, 512, 0, stream>>>(h1, Wih_f1, b_f1, Wih_b1, b_b1, pf, pb);
    k_scan<<<2, 512, 0, stream>>>(pf, Whh_f1, pb, Whh_b1, h2);

    k_headmod<<<T_SEQ, 256, 0, stream>>>(h2, FOH, FOM, hidB, headp, modv);
    dim3 gs(64, 64), bs(16, 16);
    k_score<<<gs, bs, 0, stream>>>(headp, modv, outW, out);
}